// Round 1
// baseline (1595.622 us; speedup 1.0000x reference)
//
#include <hip/hip_runtime.h>

#define BB 2
#define NN 1024
#define N1 1025
#define DM 128
#define NH 8
#define DK 16
#define DFF 512
#define NBUK 32
#define NLAYERS 3
#define KNN_K 10
#define ADJW 17          // 1025 bits -> 17 u64 words per row
#define BIGF 3.0e38f

// ---------------------------------------------------------------- embed
// h = coords @ in_W.T + in_b ; g row = gnode
__global__ void embed_kernel(const float* __restrict__ coords, const float* __restrict__ inW,
                             const float* __restrict__ inb, const float* __restrict__ gnode,
                             float* __restrict__ X) {
  int idx = blockIdx.x * 256 + threadIdx.x;
  if (idx >= BB * N1 * DM) return;
  int d = idx % DM; int r = idx / DM; int n = r % N1; int b = r / N1;
  float v;
  if (n < NN) {
    float cx = coords[(b * NN + n) * 2 + 0], cy = coords[(b * NN + n) * 2 + 1];
    v = cx * inW[d * 2 + 0] + cy * inW[d * 2 + 1] + inb[d];
  } else {
    v = gnode[d];
  }
  X[idx] = v;
}

// ---------------------------------------------------------------- bucket
__global__ void bucket_kernel(const float* __restrict__ coords, unsigned char* __restrict__ bucket) {
  int idx = blockIdx.x * 256 + threadIdx.x;
  if (idx >= BB * N1 * N1) return;
  int j = idx % N1; int r = idx / N1; int i = r % N1; int b = r / N1;
  float xi = 0.f, yi = 0.f, xj = 0.f, yj = 0.f;
  if (i < NN) { xi = coords[(b * NN + i) * 2]; yi = coords[(b * NN + i) * 2 + 1]; }
  if (j < NN) { xj = coords[(b * NN + j) * 2]; yj = coords[(b * NN + j) * 2 + 1]; }
  float dx = xi - xj, dy = yi - yj;
  float dist = sqrtf(dx * dx + dy * dy);
  int bu = (int)(dist * 32.0f);
  bu = bu < 0 ? 0 : (bu > 31 ? 31 : bu);
  bucket[idx] = (unsigned char)bu;
}

// ---------------------------------------------------------------- g += mean(h)
__global__ void g_update_kernel(float* __restrict__ X) {
  int d = blockIdx.x; int b = blockIdx.y; int lane = threadIdx.x;  // 64 threads
  float s = 0.f;
  for (int n = lane; n < NN; n += 64) s += X[((size_t)b * N1 + n) * DM + d];
  for (int o = 32; o; o >>= 1) s += __shfl_down(s, o);
  if (lane == 0) X[((size_t)b * N1 + NN) * DM + d] += s * (1.0f / NN);
}

// ---------------------------------------------------------------- pool = mean(h)
__global__ void pool_kernel(const float* __restrict__ X, float* __restrict__ pool) {
  int d = blockIdx.x; int b = blockIdx.y; int lane = threadIdx.x;
  float s = 0.f;
  for (int n = lane; n < NN; n += 64) s += X[((size_t)b * N1 + n) * DM + d];
  for (int o = 32; o; o >>= 1) s += __shfl_down(s, o);
  if (lane == 0) pool[b * DM + d] = s * (1.0f / NN);
}

// ---------------------------------------------------------------- row squared norms
__global__ void rowsq_kernel(const float* __restrict__ X, float* __restrict__ sq) {
  int idx = blockIdx.x * 64 + threadIdx.x;
  if (idx >= BB * NN) return;
  int n = idx % NN, b = idx / NN;
  const float* row = X + ((size_t)b * N1 + n) * DM;
  float s = 0.f;
  #pragma unroll 8
  for (int d = 0; d < DM; d += 4) {
    float4 v = *(const float4*)(row + d);
    s += v.x * v.x + v.y * v.y + v.z * v.z + v.w * v.w;
  }
  sq[idx] = s;
}

// ---------------------------------------------------------------- kNN -> adjacency bits
// 4 queries per block; d2 = sqi + sqj - 2*dot, diag = +inf; iterative top-10 (ties -> lowest idx)
__global__ __launch_bounds__(256) void knn_kernel(const float* __restrict__ X,
                                                  const float* __restrict__ sqb,
                                                  unsigned long long* __restrict__ adj) {
  __shared__ float hi[4][DM];
  __shared__ float dd[4][NN];
  __shared__ float rv[4];
  __shared__ int ri[4];
  int blk = blockIdx.x;
  int b = blk / (NN / 4);
  int i0 = (blk % (NN / 4)) * 4;
  int t = threadIdx.x;
  int lane = t & 63, w = t >> 6;

  for (int x = t; x < 4 * DM; x += 256)
    hi[x >> 7][x & 127] = X[((size_t)b * N1 + i0 + (x >> 7)) * DM + (x & 127)];
  __syncthreads();

  float sqi0 = sqb[b * NN + i0 + 0];
  float sqi1 = sqb[b * NN + i0 + 1];
  float sqi2 = sqb[b * NN + i0 + 2];
  float sqi3 = sqb[b * NN + i0 + 3];

  for (int j = t; j < NN; j += 256) {
    const float* row = X + ((size_t)b * N1 + j) * DM;
    float d0 = 0.f, d1 = 0.f, d2v = 0.f, d3 = 0.f;
    #pragma unroll 8
    for (int d = 0; d < DM; d += 4) {
      float4 v = *(const float4*)(row + d);
      d0 += hi[0][d] * v.x + hi[0][d + 1] * v.y + hi[0][d + 2] * v.z + hi[0][d + 3] * v.w;
      d1 += hi[1][d] * v.x + hi[1][d + 1] * v.y + hi[1][d + 2] * v.z + hi[1][d + 3] * v.w;
      d2v += hi[2][d] * v.x + hi[2][d + 1] * v.y + hi[2][d + 2] * v.z + hi[2][d + 3] * v.w;
      d3 += hi[3][d] * v.x + hi[3][d + 1] * v.y + hi[3][d + 2] * v.z + hi[3][d + 3] * v.w;
    }
    float sj = sqb[b * NN + j];
    dd[0][j] = (j == i0 + 0) ? BIGF : (sqi0 + sj - 2.f * d0);
    dd[1][j] = (j == i0 + 1) ? BIGF : (sqi1 + sj - 2.f * d1);
    dd[2][j] = (j == i0 + 2) ? BIGF : (sqi2 + sj - 2.f * d2v);
    dd[3][j] = (j == i0 + 3) ? BIGF : (sqi3 + sj - 2.f * d3);
  }
  __syncthreads();

  for (int q = 0; q < 4; ++q) {
    int i = i0 + q;
    for (int it = 0; it < KNN_K; ++it) {
      float bv = BIGF; int bi = 0x7fffffff;
      for (int j = t; j < NN; j += 256) {
        float v = dd[q][j];
        if (v < bv) { bv = v; bi = j; }
      }
      for (int o = 32; o; o >>= 1) {
        float ov = __shfl_down(bv, o); int oi = __shfl_down(bi, o);
        if (ov < bv || (ov == bv && oi < bi)) { bv = ov; bi = oi; }
      }
      if (lane == 0) { rv[w] = bv; ri[w] = bi; }
      __syncthreads();
      if (t == 0) {
        float fv = rv[0]; int fi = ri[0];
        for (int k = 1; k < 4; ++k)
          if (rv[k] < fv || (rv[k] == fv && ri[k] < fi)) { fv = rv[k]; fi = ri[k]; }
        dd[q][fi] = BIGF;
        atomicOr(&adj[((size_t)b * N1 + i) * ADJW + (fi >> 6)], 1ull << (fi & 63));
        atomicOr(&adj[((size_t)b * N1 + fi) * ADJW + (i >> 6)], 1ull << (i & 63));
      }
      __syncthreads();
    }
  }
}

// ---------------------------------------------------------------- generic projection
// out[m][o] = act( sum_k in[m][k]*W[o][k] (+bias[o]) ) (+res[m][o])
#define KC 128
__global__ __launch_bounds__(256) void proj_kernel(
    const float* __restrict__ in, const float* __restrict__ W,
    const float* __restrict__ bias, const float* __restrict__ res,
    float* __restrict__ out, int M, int Kdim, int Nout, int relu) {
  __shared__ float Wt[KC][65];
  int o = threadIdx.x & 63;
  int rg = threadIdx.x >> 6;        // 0..3, wave id
  int o0 = blockIdx.y * 64;
  int m0 = blockIdx.x * 32;
  float acc[8];
  #pragma unroll
  for (int r = 0; r < 8; ++r) acc[r] = 0.f;

  for (int k0 = 0; k0 < Kdim; k0 += KC) {
    int kk = threadIdx.x & 127;
    int orow = threadIdx.x >> 7;
    for (int oo = orow; oo < 64; oo += 2)
      Wt[kk][oo] = W[(size_t)(o0 + oo) * Kdim + k0 + kk];
    __syncthreads();
    for (int r = 0; r < 8; ++r) {
      int mm = m0 + rg * 8 + r;
      if (mm < M) {
        const float* irow = in + (size_t)mm * Kdim + k0;
        float a = acc[r];
        #pragma unroll
        for (int k = 0; k < KC; k += 4) {
          float4 iv = *(const float4*)(irow + k);
          a += iv.x * Wt[k][o] + iv.y * Wt[k + 1][o] + iv.z * Wt[k + 2][o] + iv.w * Wt[k + 3][o];
        }
        acc[r] = a;
      }
    }
    __syncthreads();
  }

  for (int r = 0; r < 8; ++r) {
    int mm = m0 + rg * 8 + r;
    if (mm >= M) continue;
    float v = acc[r];
    if (bias) v += bias[o0 + o];
    if (relu) v = fmaxf(v, 0.f);
    if (res) v += res[(size_t)mm * Nout + o0 + o];
    out[(size_t)mm * Nout + o0 + o] = v;
  }
}

// ---------------------------------------------------------------- attention (flash-style)
// one wave per query, 4 queries per block, K/V chunks staged in LDS (transposed [DK][64])
__global__ __launch_bounds__(256) void attn_kernel(
    const float* __restrict__ Q, const float* __restrict__ Kb, const float* __restrict__ Vb,
    const float* __restrict__ emb_l, const unsigned char* __restrict__ bucket,
    const unsigned long long* __restrict__ adj, float* __restrict__ ctx) {
  __shared__ float Ks[DK][65];
  __shared__ float Vs[DK][65];
  int blk = blockIdx.x;
  int itile = blk % 257; int rem = blk / 257;
  int h = rem % NH; int b = rem / NH;
  int t = threadIdx.x;
  int lane = t & 63, w = t >> 6;
  int i = itile * 4 + w;          // may exceed 1024 for last tile
  int iq = i > NN ? NN : i;

  const float* qrow = Q + ((size_t)b * N1 + iq) * DM + h * DK;
  float qv[DK];
  #pragma unroll
  for (int d = 0; d < DK; d += 4) {
    float4 v = *(const float4*)(qrow + d);
    qv[d] = v.x; qv[d + 1] = v.y; qv[d + 2] = v.z; qv[d + 3] = v.w;
  }
  // per-bucket rel bias table, lanes 0..31 hold bucket k = lane
  float qe = 0.f;
  {
    int k = lane & 31;
    const float* er = emb_l + (size_t)k * DM + h * DK;
    #pragma unroll
    for (int d = 0; d < DK; ++d) qe += qv[d] * er[d];
  }

  const unsigned long long* adjrow = adj + ((size_t)b * N1 + iq) * ADJW;
  const unsigned char* brow = bucket + ((size_t)b * N1 + iq) * N1;

  float m = -1e30f, l = 0.f;
  float acc[DK];
  #pragma unroll
  for (int d = 0; d < DK; ++d) acc[d] = 0.f;

  for (int j0 = 0; j0 < N1; j0 += 64) {
    __syncthreads();
    {
      int jl = t >> 2, f = (t & 3) * 4;
      int jg = j0 + jl; if (jg > NN) jg = NN;
      const float* kr = Kb + ((size_t)b * N1 + jg) * DM + h * DK + f;
      const float* vr = Vb + ((size_t)b * N1 + jg) * DM + h * DK + f;
      float4 kv = *(const float4*)kr;
      float4 vv = *(const float4*)vr;
      Ks[f + 0][jl] = kv.x; Ks[f + 1][jl] = kv.y; Ks[f + 2][jl] = kv.z; Ks[f + 3][jl] = kv.w;
      Vs[f + 0][jl] = vv.x; Vs[f + 1][jl] = vv.y; Vs[f + 2][jl] = vv.z; Vs[f + 3][jl] = vv.w;
    }
    __syncthreads();

    int j = j0 + lane;
    bool valid = (j < N1) && (i < N1);
    int jc = j > NN ? NN : j;

    float s = 0.f;
    #pragma unroll
    for (int d = 0; d < DK; ++d) s += qv[d] * Ks[d][lane];

    bool conn;
    if (iq == NN || jc == NN || iq == 0 || jc == 0 || iq == jc) {
      conn = true;
    } else {
      int di = iq - jc; if (di < 0) di = -di;
      conn = ((iq >> 7) == (jc >> 7) && di <= 11)
          || ((adjrow[jc >> 6] >> (jc & 63)) & 1ull);
    }
    float rel = __shfl(qe, (int)brow[jc]);
    s = s * 0.25f + rel + (conn ? 0.f : -1.0e9f);
    if (!valid) s = -BIGF;

    float mn = fmaxf(m, s);
    float p = __expf(s - mn); if (!valid) p = 0.f;
    float sc = __expf(m - mn);
    l = l * sc + p;
    #pragma unroll
    for (int d = 0; d < DK; ++d) acc[d] = acc[d] * sc + p * Vs[d][lane];
    m = mn;
  }

  // cross-lane combine (butterfly over 64 lanes)
  for (int off = 1; off < 64; off <<= 1) {
    float om = __shfl_xor(m, off);
    float ol = __shfl_xor(l, off);
    float mn = fmaxf(m, om);
    float e1 = __expf(m - mn), e2 = __expf(om - mn);
    l = l * e1 + ol * e2;
    #pragma unroll
    for (int d = 0; d < DK; ++d) {
      float oa = __shfl_xor(acc[d], off);
      acc[d] = acc[d] * e1 + oa * e2;
    }
    m = mn;
  }

  if (lane == 0 && i < N1) {
    float inv = 1.0f / l;
    float* orow = ctx + ((size_t)b * N1 + i) * DM + h * DK;
    #pragma unroll
    for (int d = 0; d < DK; ++d) orow[d] = acc[d] * inv;
  }
}

// ---------------------------------------------------------------- instance norm over nodes
__global__ void inorm_kernel(float* __restrict__ X, const float* __restrict__ w,
                             const float* __restrict__ b) {
  int d = blockIdx.x; int bb = blockIdx.y; int lane = threadIdx.x;  // 64 threads
  float s = 0.f;
  for (int n = lane; n < N1; n += 64) s += X[((size_t)bb * N1 + n) * DM + d];
  for (int o = 32; o; o >>= 1) s += __shfl_down(s, o);
  float mu = __shfl(s, 0) * (1.0f / N1);
  float v = 0.f;
  for (int n = lane; n < N1; n += 64) {
    float t = X[((size_t)bb * N1 + n) * DM + d] - mu;
    v += t * t;
  }
  for (int o = 32; o; o >>= 1) v += __shfl_down(v, o);
  float var = __shfl(v, 0) * (1.0f / N1);
  float scv = rsqrtf(var + 1e-5f) * w[d];
  float sh = b[d];
  for (int n = lane; n < N1; n += 64) {
    size_t id = ((size_t)bb * N1 + n) * DM + d;
    X[id] = (X[id] - mu) * scv + sh;
  }
}

// ---------------------------------------------------------------- p_multi
__global__ void pmulti_kernel(const float* __restrict__ pools, float* __restrict__ pm,
                              float* __restrict__ out_pm) {
  int idx = blockIdx.x * 64 + threadIdx.x;
  if (idx >= BB * DM) return;
  float v = (pools[idx] + pools[BB * DM + idx] + pools[2 * BB * DM + idx]) * (1.0f / 3.0f);
  pm[idx] = v;
  out_pm[idx] = v;
}

// ---------------------------------------------------------------- tmp = h + p_multi
__global__ void addpm_kernel(const float* __restrict__ X, const float* __restrict__ pm,
                             float* __restrict__ tmp) {
  int idx = blockIdx.x * 256 + threadIdx.x;
  if (idx >= BB * NN * DM) return;
  int d = idx % DM; int n = (idx / DM) % NN; int b = idx / (DM * NN);
  tmp[idx] = X[((size_t)b * N1 + n) * DM + d] + pm[b * DM + d];
}

// ================================================================ launch
extern "C" void kernel_launch(void* const* d_in, const int* in_sizes, int n_in,
                              void* d_out, int out_size, void* d_ws, size_t ws_size,
                              hipStream_t stream) {
  const float* coords = (const float*)d_in[0];
  const float* inW    = (const float*)d_in[1];
  const float* inb    = (const float*)d_in[2];
  const float* gnode  = (const float*)d_in[3];
  const float* Wq     = (const float*)d_in[4];
  const float* Wk     = (const float*)d_in[5];
  const float* Wv     = (const float*)d_in[6];
  const float* Wo     = (const float*)d_in[7];
  const float* emb    = (const float*)d_in[8];
  const float* W1     = (const float*)d_in[9];
  const float* b1     = (const float*)d_in[10];
  const float* W2     = (const float*)d_in[11];
  const float* b2     = (const float*)d_in[12];
  const float* n1w    = (const float*)d_in[13];
  const float* n1b    = (const float*)d_in[14];
  const float* n2w    = (const float*)d_in[15];
  const float* n2b    = (const float*)d_in[16];
  const float* outW   = (const float*)d_in[17];
  const float* outb   = (const float*)d_in[18];
  float* out = (float*)d_out;

  char* wsp = (char*)d_ws;
  size_t off = 0;
  auto alloc = [&](size_t bytes) -> void* {
    off = (off + 255) & ~(size_t)255;
    void* p = wsp + off;
    off += bytes;
    return p;
  };
  const size_t XB = (size_t)BB * N1 * DM * 4;
  float* X0   = (float*)alloc(XB);
  float* X1   = (float*)alloc(XB);
  float* Qb   = (float*)alloc(XB);
  float* Kbuf = (float*)alloc(XB);
  float* Vbuf = (float*)alloc(XB);
  float* Cb   = (float*)alloc(XB);
  float* Yb   = (float*)alloc(XB);
  float* Fb   = (float*)alloc((size_t)BB * N1 * DFF * 4);
  unsigned char* buck = (unsigned char*)alloc((size_t)BB * N1 * N1);
  unsigned long long* adj = (unsigned long long*)alloc((size_t)BB * N1 * ADJW * 8);
  float* sqb   = (float*)alloc((size_t)BB * NN * 4);
  float* pools = (float*)alloc((size_t)NLAYERS * BB * DM * 4);
  float* pm    = (float*)alloc((size_t)BB * DM * 4);
  float* tmp   = (float*)alloc((size_t)BB * NN * DM * 4);

  embed_kernel<<<(BB * N1 * DM + 255) / 256, 256, 0, stream>>>(coords, inW, inb, gnode, X0);
  bucket_kernel<<<(BB * N1 * N1 + 255) / 256, 256, 0, stream>>>(coords, buck);

  float* Xin = X0; float* Xout = X1;
  const int M = BB * N1;
  for (int l = 0; l < NLAYERS; ++l) {
    g_update_kernel<<<dim3(DM, BB), 64, 0, stream>>>(Xin);
    hipMemsetAsync(adj, 0, (size_t)BB * N1 * ADJW * 8, stream);
    rowsq_kernel<<<(BB * NN + 63) / 64, 64, 0, stream>>>(Xin, sqb);
    knn_kernel<<<BB * NN / 4, 256, 0, stream>>>(Xin, sqb, adj);

    proj_kernel<<<dim3((M + 31) / 32, DM / 64), 256, 0, stream>>>(
        Xin, Wq + (size_t)l * DM * DM, nullptr, nullptr, Qb, M, DM, DM, 0);
    proj_kernel<<<dim3((M + 31) / 32, DM / 64), 256, 0, stream>>>(
        Xin, Wk + (size_t)l * DM * DM, nullptr, nullptr, Kbuf, M, DM, DM, 0);
    proj_kernel<<<dim3((M + 31) / 32, DM / 64), 256, 0, stream>>>(
        Xin, Wv + (size_t)l * DM * DM, nullptr, nullptr, Vbuf, M, DM, DM, 0);

    attn_kernel<<<BB * NH * 257, 256, 0, stream>>>(
        Qb, Kbuf, Vbuf, emb + (size_t)l * NBUK * DM, buck, adj, Cb);

    proj_kernel<<<dim3((M + 31) / 32, DM / 64), 256, 0, stream>>>(
        Cb, Wo + (size_t)l * DM * DM, nullptr, Xin, Yb, M, DM, DM, 0);
    inorm_kernel<<<dim3(DM, BB), 64, 0, stream>>>(Yb, n1w + l * DM, n1b + l * DM);

    proj_kernel<<<dim3((M + 31) / 32, DFF / 64), 256, 0, stream>>>(
        Yb, W1 + (size_t)l * DFF * DM, b1 + l * DFF, nullptr, Fb, M, DM, DFF, 1);
    proj_kernel<<<dim3((M + 31) / 32, DM / 64), 256, 0, stream>>>(
        Fb, W2 + (size_t)l * DM * DFF, b2 + l * DM, Yb, Xout, M, DFF, DM, 0);
    inorm_kernel<<<dim3(DM, BB), 64, 0, stream>>>(Xout, n2w + l * DM, n2b + l * DM);

    pool_kernel<<<dim3(DM, BB), 64, 0, stream>>>(Xout, pools + (size_t)l * BB * DM);

    float* t2 = Xin; Xin = Xout; Xout = t2;
  }

  pmulti_kernel<<<(BB * DM + 63) / 64, 64, 0, stream>>>(pools, pm, out + (size_t)BB * NN * DM);
  addpm_kernel<<<(BB * NN * DM + 255) / 256, 256, 0, stream>>>(Xin, pm, tmp);
  proj_kernel<<<dim3((BB * NN + 31) / 32, DM / 64), 256, 0, stream>>>(
      tmp, outW, outb, nullptr, out, BB * NN, DM, DM, 0);
}

// Round 2
// 879.009 us; speedup vs baseline: 1.8153x; 1.8153x over previous
//
#include <hip/hip_runtime.h>

#define BB 2
#define NN 1024
#define N1 1025
#define DM 128
#define NH 8
#define DK 16
#define DFF 512
#define NBUK 32
#define NLAYERS 3
#define KNN_K 10
#define ADJW 17          // 1025 bits -> 17 u64 words per row
#define BIGF 3.0e38f

typedef __attribute__((ext_vector_type(8))) short bf8;
typedef __attribute__((ext_vector_type(4))) float f4;

__device__ __forceinline__ short f2bf(float x) {
  unsigned u = __float_as_uint(x);
  return (short)((u + 0x7fff + ((u >> 16) & 1)) >> 16);   // RNE
}

// ---------------------------------------------------------------- embed
__global__ void embed_kernel(const float* __restrict__ coords, const float* __restrict__ inW,
                             const float* __restrict__ inb, const float* __restrict__ gnode,
                             float* __restrict__ X) {
  int idx = blockIdx.x * 256 + threadIdx.x;
  if (idx >= BB * N1 * DM) return;
  int d = idx % DM; int r = idx / DM; int n = r % N1; int b = r / N1;
  float v;
  if (n < NN) {
    float cx = coords[(b * NN + n) * 2 + 0], cy = coords[(b * NN + n) * 2 + 1];
    v = cx * inW[d * 2 + 0] + cy * inW[d * 2 + 1] + inb[d];
  } else {
    v = gnode[d];
  }
  X[idx] = v;
}

// ---------------------------------------------------------------- bucket
__global__ void bucket_kernel(const float* __restrict__ coords, unsigned char* __restrict__ bucket) {
  int idx = blockIdx.x * 256 + threadIdx.x;
  if (idx >= BB * N1 * N1) return;
  int j = idx % N1; int r = idx / N1; int i = r % N1; int b = r / N1;
  float xi = 0.f, yi = 0.f, xj = 0.f, yj = 0.f;
  if (i < NN) { xi = coords[(b * NN + i) * 2]; yi = coords[(b * NN + i) * 2 + 1]; }
  if (j < NN) { xj = coords[(b * NN + j) * 2]; yj = coords[(b * NN + j) * 2 + 1]; }
  float dx = xi - xj, dy = yi - yj;
  float dist = sqrtf(dx * dx + dy * dy);
  int bu = (int)(dist * 32.0f);
  bu = bu < 0 ? 0 : (bu > 31 ? 31 : bu);
  bucket[idx] = (unsigned char)bu;
}

// ---------------------------------------------------------------- g += mean(h)
__global__ void g_update_kernel(float* __restrict__ X) {
  int d = blockIdx.x; int b = blockIdx.y; int lane = threadIdx.x;  // 64 threads
  float s = 0.f;
  for (int n = lane; n < NN; n += 64) s += X[((size_t)b * N1 + n) * DM + d];
  for (int o = 32; o; o >>= 1) s += __shfl_down(s, o);
  if (lane == 0) X[((size_t)b * N1 + NN) * DM + d] += s * (1.0f / NN);
}

// ---------------------------------------------------------------- pool = mean(h)
__global__ void pool_kernel(const float* __restrict__ X, float* __restrict__ pool) {
  int d = blockIdx.x; int b = blockIdx.y; int lane = threadIdx.x;
  float s = 0.f;
  for (int n = lane; n < NN; n += 64) s += X[((size_t)b * N1 + n) * DM + d];
  for (int o = 32; o; o >>= 1) s += __shfl_down(s, o);
  if (lane == 0) pool[b * DM + d] = s * (1.0f / NN);
}

// ---------------------------------------------------------------- row squared norms
__global__ void rowsq_kernel(const float* __restrict__ X, float* __restrict__ sq) {
  int idx = blockIdx.x * 64 + threadIdx.x;
  if (idx >= BB * NN) return;
  int n = idx % NN, b = idx / NN;
  const float* row = X + ((size_t)b * N1 + n) * DM;
  float s = 0.f;
  #pragma unroll 8
  for (int d = 0; d < DM; d += 4) {
    float4 v = *(const float4*)(row + d);
    s += v.x * v.x + v.y * v.y + v.z * v.z + v.w * v.w;
  }
  sq[idx] = s;
}

// ---------------------------------------------------------------- kNN -> adjacency bits
__global__ __launch_bounds__(256) void knn_kernel(const float* __restrict__ X,
                                                  const float* __restrict__ sqb,
                                                  unsigned long long* __restrict__ adj) {
  __shared__ float hi[4][DM];
  __shared__ float dd[4][NN];
  __shared__ float rv[4];
  __shared__ int ri[4];
  int blk = blockIdx.x;
  int b = blk / (NN / 4);
  int i0 = (blk % (NN / 4)) * 4;
  int t = threadIdx.x;
  int lane = t & 63, w = t >> 6;

  for (int x = t; x < 4 * DM; x += 256)
    hi[x >> 7][x & 127] = X[((size_t)b * N1 + i0 + (x >> 7)) * DM + (x & 127)];
  __syncthreads();

  float sqi0 = sqb[b * NN + i0 + 0];
  float sqi1 = sqb[b * NN + i0 + 1];
  float sqi2 = sqb[b * NN + i0 + 2];
  float sqi3 = sqb[b * NN + i0 + 3];

  for (int j = t; j < NN; j += 256) {
    const float* row = X + ((size_t)b * N1 + j) * DM;
    float d0 = 0.f, d1 = 0.f, d2v = 0.f, d3 = 0.f;
    #pragma unroll 8
    for (int d = 0; d < DM; d += 4) {
      float4 v = *(const float4*)(row + d);
      d0 += hi[0][d] * v.x + hi[0][d + 1] * v.y + hi[0][d + 2] * v.z + hi[0][d + 3] * v.w;
      d1 += hi[1][d] * v.x + hi[1][d + 1] * v.y + hi[1][d + 2] * v.z + hi[1][d + 3] * v.w;
      d2v += hi[2][d] * v.x + hi[2][d + 1] * v.y + hi[2][d + 2] * v.z + hi[2][d + 3] * v.w;
      d3 += hi[3][d] * v.x + hi[3][d + 1] * v.y + hi[3][d + 2] * v.z + hi[3][d + 3] * v.w;
    }
    float sj = sqb[b * NN + j];
    dd[0][j] = (j == i0 + 0) ? BIGF : (sqi0 + sj - 2.f * d0);
    dd[1][j] = (j == i0 + 1) ? BIGF : (sqi1 + sj - 2.f * d1);
    dd[2][j] = (j == i0 + 2) ? BIGF : (sqi2 + sj - 2.f * d2v);
    dd[3][j] = (j == i0 + 3) ? BIGF : (sqi3 + sj - 2.f * d3);
  }
  __syncthreads();

  for (int q = 0; q < 4; ++q) {
    int i = i0 + q;
    for (int it = 0; it < KNN_K; ++it) {
      float bv = BIGF; int bi = 0x7fffffff;
      for (int j = t; j < NN; j += 256) {
        float v = dd[q][j];
        if (v < bv) { bv = v; bi = j; }
      }
      for (int o = 32; o; o >>= 1) {
        float ov = __shfl_down(bv, o); int oi = __shfl_down(bi, o);
        if (ov < bv || (ov == bv && oi < bi)) { bv = ov; bi = oi; }
      }
      if (lane == 0) { rv[w] = bv; ri[w] = bi; }
      __syncthreads();
      if (t == 0) {
        float fv = rv[0]; int fi = ri[0];
        for (int k = 1; k < 4; ++k)
          if (rv[k] < fv || (rv[k] == fv && ri[k] < fi)) { fv = rv[k]; fi = ri[k]; }
        dd[q][fi] = BIGF;
        atomicOr(&adj[((size_t)b * N1 + i) * ADJW + (fi >> 6)], 1ull << (fi & 63));
        atomicOr(&adj[((size_t)b * N1 + fi) * ADJW + (i >> 6)], 1ull << (i & 63));
      }
      __syncthreads();
    }
  }
}

// ---------------------------------------------------------------- bf16 MFMA GEMM
// out[m][n] = act( sum_k in[m][k]*W[n][k] (+bias) ) (+res)
// tile 32(M) x 64(N) x 64(K); fp32 -> bf16 conversion during LDS staging
#define BMT 32
#define BNT 64
#define BKT 64
#define LDKG 72   // BKT + 8 pad: frag reads land 2-way (free), rows 16B aligned

__device__ __forceinline__ void gemm_core(
    const float* __restrict__ in, const float* __restrict__ W,
    const float* __restrict__ bias, const float* __restrict__ res,
    float* __restrict__ out, int M, int Kdim, int Nout, int relu,
    int m0, int n0) {
  __shared__ short As[BMT][LDKG];
  __shared__ short Bs[BNT][LDKG];
  int t = threadIdx.x;
  int lane = t & 63, w = t >> 6;
  int wm = (w >> 1) * 16, wn = (w & 1) * 32;
  int quad = lane >> 4, r = lane & 15;

  f4 acc0 = {0.f, 0.f, 0.f, 0.f}, acc1 = {0.f, 0.f, 0.f, 0.f};

  int ar = t >> 3, as_ = (t & 7) * 8;     // A stage: 32 rows x 8 segs
  int br = t >> 2, bs_ = (t & 3) * 16;    // B stage: 64 rows x 4 segs

  for (int k0 = 0; k0 < Kdim; k0 += BKT) {
    {
      int m = m0 + ar;
      short* d = &As[ar][as_];
      if (m < M) {
        const float* p = in + (size_t)m * Kdim + k0 + as_;
        float4 v0 = *(const float4*)p;
        float4 v1 = *(const float4*)(p + 4);
        d[0] = f2bf(v0.x); d[1] = f2bf(v0.y); d[2] = f2bf(v0.z); d[3] = f2bf(v0.w);
        d[4] = f2bf(v1.x); d[5] = f2bf(v1.y); d[6] = f2bf(v1.z); d[7] = f2bf(v1.w);
      } else {
        #pragma unroll
        for (int q = 0; q < 8; ++q) d[q] = 0;
      }
    }
    {
      const float* p = W + (size_t)(n0 + br) * Kdim + k0 + bs_;
      short* d = &Bs[br][bs_];
      #pragma unroll
      for (int q = 0; q < 16; q += 4) {
        float4 v = *(const float4*)(p + q);
        d[q] = f2bf(v.x); d[q + 1] = f2bf(v.y); d[q + 2] = f2bf(v.z); d[q + 3] = f2bf(v.w);
      }
    }
    __syncthreads();
    #pragma unroll
    for (int ks = 0; ks < BKT; ks += 32) {
      bf8 a  = *(const bf8*)&As[wm + r][ks + quad * 8];
      bf8 b0 = *(const bf8*)&Bs[wn + r][ks + quad * 8];
      bf8 b1 = *(const bf8*)&Bs[wn + 16 + r][ks + quad * 8];
      acc0 = __builtin_amdgcn_mfma_f32_16x16x32_bf16(a, b0, acc0, 0, 0, 0);
      acc1 = __builtin_amdgcn_mfma_f32_16x16x32_bf16(a, b1, acc1, 0, 0, 0);
    }
    __syncthreads();
  }

  #pragma unroll
  for (int tt = 0; tt < 2; ++tt) {
    f4 a = tt ? acc1 : acc0;
    int n = n0 + wn + tt * 16 + r;
    #pragma unroll
    for (int reg = 0; reg < 4; ++reg) {
      int m = m0 + wm + quad * 4 + reg;   // C layout: col=lane&15, row=quad*4+reg
      if (m < M) {
        float v = a[reg];
        if (bias) v += bias[n];
        if (relu) v = fmaxf(v, 0.f);
        if (res) v += res[(size_t)m * Nout + n];
        out[(size_t)m * Nout + n] = v;
      }
    }
  }
}

__global__ __launch_bounds__(256) void gemm_kernel(
    const float* __restrict__ in, const float* __restrict__ W,
    const float* __restrict__ bias, const float* __restrict__ res,
    float* __restrict__ out, int M, int Kdim, int Nout, int relu) {
  gemm_core(in, W, bias, res, out, M, Kdim, Nout, relu,
            blockIdx.x * BMT, blockIdx.y * BNT);
}

__global__ __launch_bounds__(256) void gemm_qkv_kernel(
    const float* __restrict__ in, const float* __restrict__ Wq,
    const float* __restrict__ Wk, const float* __restrict__ Wv,
    float* __restrict__ Qo, float* __restrict__ Ko, float* __restrict__ Vo,
    int M) {
  const float* W = blockIdx.z == 0 ? Wq : (blockIdx.z == 1 ? Wk : Wv);
  float* out = blockIdx.z == 0 ? Qo : (blockIdx.z == 1 ? Ko : Vo);
  gemm_core(in, W, nullptr, nullptr, out, M, DM, DM, 0,
            blockIdx.x * BMT, blockIdx.y * BNT);
}

// ---------------------------------------------------------------- attention (flash-style)
__global__ __launch_bounds__(256) void attn_kernel(
    const float* __restrict__ Q, const float* __restrict__ Kb, const float* __restrict__ Vb,
    const float* __restrict__ emb_l, const unsigned char* __restrict__ bucket,
    const unsigned long long* __restrict__ adj, float* __restrict__ ctx) {
  __shared__ float Ks[DK][65];
  __shared__ float Vs[DK][65];
  int blk = blockIdx.x;
  int itile = blk % 257; int rem = blk / 257;
  int h = rem % NH; int b = rem / NH;
  int t = threadIdx.x;
  int lane = t & 63, w = t >> 6;
  int i = itile * 4 + w;
  int iq = i > NN ? NN : i;

  const float* qrow = Q + ((size_t)b * N1 + iq) * DM + h * DK;
  float qv[DK];
  #pragma unroll
  for (int d = 0; d < DK; d += 4) {
    float4 v = *(const float4*)(qrow + d);
    qv[d] = v.x; qv[d + 1] = v.y; qv[d + 2] = v.z; qv[d + 3] = v.w;
  }
  float qe = 0.f;
  {
    int k = lane & 31;
    const float* er = emb_l + (size_t)k * DM + h * DK;
    #pragma unroll
    for (int d = 0; d < DK; ++d) qe += qv[d] * er[d];
  }

  const unsigned long long* adjrow = adj + ((size_t)b * N1 + iq) * ADJW;
  const unsigned char* brow = bucket + ((size_t)b * N1 + iq) * N1;

  float m = -1e30f, l = 0.f;
  float acc[DK];
  #pragma unroll
  for (int d = 0; d < DK; ++d) acc[d] = 0.f;

  for (int j0 = 0; j0 < N1; j0 += 64) {
    __syncthreads();
    {
      int jl = t >> 2, f = (t & 3) * 4;
      int jg = j0 + jl; if (jg > NN) jg = NN;
      const float* kr = Kb + ((size_t)b * N1 + jg) * DM + h * DK + f;
      const float* vr = Vb + ((size_t)b * N1 + jg) * DM + h * DK + f;
      float4 kv = *(const float4*)kr;
      float4 vv = *(const float4*)vr;
      Ks[f + 0][jl] = kv.x; Ks[f + 1][jl] = kv.y; Ks[f + 2][jl] = kv.z; Ks[f + 3][jl] = kv.w;
      Vs[f + 0][jl] = vv.x; Vs[f + 1][jl] = vv.y; Vs[f + 2][jl] = vv.z; Vs[f + 3][jl] = vv.w;
    }
    __syncthreads();

    int j = j0 + lane;
    bool valid = (j < N1) && (i < N1);
    int jc = j > NN ? NN : j;

    float s = 0.f;
    #pragma unroll
    for (int d = 0; d < DK; ++d) s += qv[d] * Ks[d][lane];

    bool conn;
    if (iq == NN || jc == NN || iq == 0 || jc == 0 || iq == jc) {
      conn = true;
    } else {
      int di = iq - jc; if (di < 0) di = -di;
      conn = ((iq >> 7) == (jc >> 7) && di <= 11)
          || ((adjrow[jc >> 6] >> (jc & 63)) & 1ull);
    }
    float rel = __shfl(qe, (int)brow[jc]);
    s = s * 0.25f + rel + (conn ? 0.f : -1.0e9f);
    if (!valid) s = -BIGF;

    float mn = fmaxf(m, s);
    float p = __expf(s - mn); if (!valid) p = 0.f;
    float sc = __expf(m - mn);
    l = l * sc + p;
    #pragma unroll
    for (int d = 0; d < DK; ++d) acc[d] = acc[d] * sc + p * Vs[d][lane];
    m = mn;
  }

  for (int off = 1; off < 64; off <<= 1) {
    float om = __shfl_xor(m, off);
    float ol = __shfl_xor(l, off);
    float mn = fmaxf(m, om);
    float e1 = __expf(m - mn), e2 = __expf(om - mn);
    l = l * e1 + ol * e2;
    #pragma unroll
    for (int d = 0; d < DK; ++d) {
      float oa = __shfl_xor(acc[d], off);
      acc[d] = acc[d] * e1 + oa * e2;
    }
    m = mn;
  }

  if (lane == 0 && i < N1) {
    float inv = 1.0f / l;
    float* orow = ctx + ((size_t)b * N1 + i) * DM + h * DK;
    #pragma unroll
    for (int d = 0; d < DK; ++d) orow[d] = acc[d] * inv;
  }
}

// ---------------------------------------------------------------- instance norm over nodes
__global__ void inorm_kernel(float* __restrict__ X, const float* __restrict__ w,
                             const float* __restrict__ b) {
  int d = blockIdx.x; int bb = blockIdx.y; int lane = threadIdx.x;
  float s = 0.f;
  for (int n = lane; n < N1; n += 64) s += X[((size_t)bb * N1 + n) * DM + d];
  for (int o = 32; o; o >>= 1) s += __shfl_down(s, o);
  float mu = __shfl(s, 0) * (1.0f / N1);
  float v = 0.f;
  for (int n = lane; n < N1; n += 64) {
    float t = X[((size_t)bb * N1 + n) * DM + d] - mu;
    v += t * t;
  }
  for (int o = 32; o; o >>= 1) v += __shfl_down(v, o);
  float var = __shfl(v, 0) * (1.0f / N1);
  float scv = rsqrtf(var + 1e-5f) * w[d];
  float sh = b[d];
  for (int n = lane; n < N1; n += 64) {
    size_t id = ((size_t)bb * N1 + n) * DM + d;
    X[id] = (X[id] - mu) * scv + sh;
  }
}

// ---------------------------------------------------------------- p_multi
__global__ void pmulti_kernel(const float* __restrict__ pools, float* __restrict__ pm,
                              float* __restrict__ out_pm) {
  int idx = blockIdx.x * 64 + threadIdx.x;
  if (idx >= BB * DM) return;
  float v = (pools[idx] + pools[BB * DM + idx] + pools[2 * BB * DM + idx]) * (1.0f / 3.0f);
  pm[idx] = v;
  out_pm[idx] = v;
}

// ---------------------------------------------------------------- tmp = h + p_multi
__global__ void addpm_kernel(const float* __restrict__ X, const float* __restrict__ pm,
                             float* __restrict__ tmp) {
  int idx = blockIdx.x * 256 + threadIdx.x;
  if (idx >= BB * NN * DM) return;
  int d = idx % DM; int n = (idx / DM) % NN; int b = idx / (DM * NN);
  tmp[idx] = X[((size_t)b * N1 + n) * DM + d] + pm[b * DM + d];
}

// ================================================================ launch
extern "C" void kernel_launch(void* const* d_in, const int* in_sizes, int n_in,
                              void* d_out, int out_size, void* d_ws, size_t ws_size,
                              hipStream_t stream) {
  const float* coords = (const float*)d_in[0];
  const float* inW    = (const float*)d_in[1];
  const float* inb    = (const float*)d_in[2];
  const float* gnode  = (const float*)d_in[3];
  const float* Wq     = (const float*)d_in[4];
  const float* Wk     = (const float*)d_in[5];
  const float* Wv     = (const float*)d_in[6];
  const float* Wo     = (const float*)d_in[7];
  const float* emb    = (const float*)d_in[8];
  const float* W1     = (const float*)d_in[9];
  const float* b1     = (const float*)d_in[10];
  const float* W2     = (const float*)d_in[11];
  const float* b2     = (const float*)d_in[12];
  const float* n1w    = (const float*)d_in[13];
  const float* n1b    = (const float*)d_in[14];
  const float* n2w    = (const float*)d_in[15];
  const float* n2b    = (const float*)d_in[16];
  const float* outW   = (const float*)d_in[17];
  const float* outb   = (const float*)d_in[18];
  float* out = (float*)d_out;

  char* wsp = (char*)d_ws;
  size_t off = 0;
  auto alloc = [&](size_t bytes) -> void* {
    off = (off + 255) & ~(size_t)255;
    void* p = wsp + off;
    off += bytes;
    return p;
  };
  const size_t XB = (size_t)BB * N1 * DM * 4;
  float* X0   = (float*)alloc(XB);
  float* X1   = (float*)alloc(XB);
  float* Qb   = (float*)alloc(XB);
  float* Kbuf = (float*)alloc(XB);
  float* Vbuf = (float*)alloc(XB);
  float* Cb   = (float*)alloc(XB);
  float* Yb   = (float*)alloc(XB);
  float* Fb   = (float*)alloc((size_t)BB * N1 * DFF * 4);
  unsigned char* buck = (unsigned char*)alloc((size_t)BB * N1 * N1);
  unsigned long long* adj = (unsigned long long*)alloc((size_t)BB * N1 * ADJW * 8);
  float* sqb   = (float*)alloc((size_t)BB * NN * 4);
  float* pools = (float*)alloc((size_t)NLAYERS * BB * DM * 4);
  float* pm    = (float*)alloc((size_t)BB * DM * 4);
  float* tmp   = (float*)alloc((size_t)BB * NN * DM * 4);

  embed_kernel<<<(BB * N1 * DM + 255) / 256, 256, 0, stream>>>(coords, inW, inb, gnode, X0);
  bucket_kernel<<<(BB * N1 * N1 + 255) / 256, 256, 0, stream>>>(coords, buck);

  float* Xin = X0; float* Xout = X1;
  const int M = BB * N1;
  const int GM = (M + BMT - 1) / BMT;   // 65
  for (int l = 0; l < NLAYERS; ++l) {
    g_update_kernel<<<dim3(DM, BB), 64, 0, stream>>>(Xin);
    hipMemsetAsync(adj, 0, (size_t)BB * N1 * ADJW * 8, stream);
    rowsq_kernel<<<(BB * NN + 63) / 64, 64, 0, stream>>>(Xin, sqb);
    knn_kernel<<<BB * NN / 4, 256, 0, stream>>>(Xin, sqb, adj);

    gemm_qkv_kernel<<<dim3(GM, DM / BNT, 3), 256, 0, stream>>>(
        Xin, Wq + (size_t)l * DM * DM, Wk + (size_t)l * DM * DM, Wv + (size_t)l * DM * DM,
        Qb, Kbuf, Vbuf, M);

    attn_kernel<<<BB * NH * 257, 256, 0, stream>>>(
        Qb, Kbuf, Vbuf, emb + (size_t)l * NBUK * DM, buck, adj, Cb);

    gemm_kernel<<<dim3(GM, DM / BNT), 256, 0, stream>>>(
        Cb, Wo + (size_t)l * DM * DM, nullptr, Xin, Yb, M, DM, DM, 0);
    inorm_kernel<<<dim3(DM, BB), 64, 0, stream>>>(Yb, n1w + l * DM, n1b + l * DM);

    gemm_kernel<<<dim3(GM, DFF / BNT), 256, 0, stream>>>(
        Yb, W1 + (size_t)l * DFF * DM, b1 + l * DFF, nullptr, Fb, M, DM, DFF, 1);
    gemm_kernel<<<dim3(GM, DM / BNT), 256, 0, stream>>>(
        Fb, W2 + (size_t)l * DM * DFF, b2 + l * DM, Yb, Xout, M, DFF, DM, 0);
    inorm_kernel<<<dim3(DM, BB), 64, 0, stream>>>(Xout, n2w + l * DM, n2b + l * DM);

    pool_kernel<<<dim3(DM, BB), 64, 0, stream>>>(Xout, pools + (size_t)l * BB * DM);

    float* t2 = Xin; Xin = Xout; Xout = t2;
  }

  pmulti_kernel<<<(BB * DM + 63) / 64, 64, 0, stream>>>(pools, pm, out + (size_t)BB * NN * DM);
  addpm_kernel<<<(BB * NN * DM + 255) / 256, 256, 0, stream>>>(Xin, pm, tmp);
  gemm_kernel<<<dim3((BB * NN + BMT - 1) / BMT, DM / BNT), 256, 0, stream>>>(
      tmp, outW, outb, nullptr, out, BB * NN, DM, DM, 0);
}

// Round 3
// 701.902 us; speedup vs baseline: 2.2733x; 1.2523x over previous
//
#include <hip/hip_runtime.h>

#define BB 2
#define NN 1024
#define N1 1025
#define DM 128
#define NH 8
#define DK 16
#define DFF 512
#define NBUK 32
#define NLAYERS 3
#define KNN_K 10
#define ADJW 17          // 1025 bits -> 17 u64 words per row
#define MW 34            // 34 u32 mask words per row (1088 bits)
#define BSTR 1088        // padded bucket row stride (bytes)
#define BIGF 3.0e38f

typedef __attribute__((ext_vector_type(8))) short bf8;
typedef __attribute__((ext_vector_type(4))) float f4;
typedef unsigned short u16;
typedef unsigned int u32;

__device__ __forceinline__ u16 f2bf(float x) {
  unsigned u = __float_as_uint(x);
  return (u16)((u + 0x7fff + ((u >> 16) & 1)) >> 16);   // RNE
}
__device__ __forceinline__ float bf2f(u16 u) {
  return __uint_as_float(((unsigned)u) << 16);
}
__device__ __forceinline__ bf8 mk8(ushort4 a, ushort4 b) {
  bf8 r;
  r[0] = (short)a.x; r[1] = (short)a.y; r[2] = (short)a.z; r[3] = (short)a.w;
  r[4] = (short)b.x; r[5] = (short)b.y; r[6] = (short)b.z; r[7] = (short)b.w;
  return r;
}

// ---------------------------------------------------------------- embed
__global__ void embed_kernel(const float* __restrict__ coords, const float* __restrict__ inW,
                             const float* __restrict__ inb, const float* __restrict__ gnode,
                             float* __restrict__ X) {
  int idx = blockIdx.x * 256 + threadIdx.x;
  if (idx >= BB * N1 * DM) return;
  int d = idx % DM; int r = idx / DM; int n = r % N1; int b = r / N1;
  float v;
  if (n < NN) {
    float cx = coords[(b * NN + n) * 2 + 0], cy = coords[(b * NN + n) * 2 + 1];
    v = cx * inW[d * 2 + 0] + cy * inW[d * 2 + 1] + inb[d];
  } else {
    v = gnode[d];
  }
  X[idx] = v;
}

// ---------------------------------------------------------------- bucket (padded rows)
__global__ void bucket_kernel(const float* __restrict__ coords, unsigned char* __restrict__ buckp) {
  int idx = blockIdx.x * 256 + threadIdx.x;
  if (idx >= BB * N1 * BSTR) return;
  int j = idx % BSTR; int r = idx / BSTR; int i = r % N1; int b = r / N1;
  unsigned char v = 0;
  if (j < N1) {
    float xi = 0.f, yi = 0.f, xj = 0.f, yj = 0.f;
    if (i < NN) { xi = coords[(b * NN + i) * 2]; yi = coords[(b * NN + i) * 2 + 1]; }
    if (j < NN) { xj = coords[(b * NN + j) * 2]; yj = coords[(b * NN + j) * 2 + 1]; }
    float dx = xi - xj, dy = yi - yj;
    float dist = sqrtf(dx * dx + dy * dy);
    int bu = (int)(dist * 32.0f);
    bu = bu < 0 ? 0 : (bu > 31 ? 31 : bu);
    v = (unsigned char)bu;
  }
  buckp[idx] = v;
}

// ---------------------------------------------------------------- g += mean(h) (layer 0 only)
__global__ void g_update_kernel(float* __restrict__ X) {
  int d = blockIdx.x; int b = blockIdx.y; int lane = threadIdx.x;  // 64 threads
  float s = 0.f;
  for (int n = lane; n < NN; n += 64) s += X[((size_t)b * N1 + n) * DM + d];
  for (int o = 32; o; o >>= 1) s += __shfl_down(s, o);
  if (lane == 0) X[((size_t)b * N1 + NN) * DM + d] += s * (1.0f / NN);
}

// ---------------------------------------------------------------- row squared norms
__global__ void rowsq_kernel(const float* __restrict__ X, float* __restrict__ sq) {
  int idx = blockIdx.x * 64 + threadIdx.x;
  if (idx >= BB * NN) return;
  int n = idx % NN, b = idx / NN;
  const float* row = X + ((size_t)b * N1 + n) * DM;
  float s = 0.f;
  #pragma unroll 8
  for (int d = 0; d < DM; d += 4) {
    float4 v = *(const float4*)(row + d);
    s += v.x * v.x + v.y * v.y + v.z * v.z + v.w * v.w;
  }
  sq[idx] = s;
}

// ---------------------------------------------------------------- kNN -> adjacency bits
__global__ __launch_bounds__(256) void knn_kernel(const float* __restrict__ X,
                                                  const float* __restrict__ sqb,
                                                  unsigned long long* __restrict__ adj) {
  __shared__ float hi[4][DM];
  __shared__ float dd[4][NN];
  int blk = blockIdx.x;
  int b = blk / (NN / 4);
  int i0 = (blk % (NN / 4)) * 4;
  int t = threadIdx.x;
  int lane = t & 63, w = t >> 6;

  for (int x = t; x < 4 * DM; x += 256)
    hi[x >> 7][x & 127] = X[((size_t)b * N1 + i0 + (x >> 7)) * DM + (x & 127)];
  __syncthreads();

  float sqi0 = sqb[b * NN + i0 + 0];
  float sqi1 = sqb[b * NN + i0 + 1];
  float sqi2 = sqb[b * NN + i0 + 2];
  float sqi3 = sqb[b * NN + i0 + 3];

  for (int j = t; j < NN; j += 256) {
    const float* row = X + ((size_t)b * N1 + j) * DM;
    float d0 = 0.f, d1 = 0.f, d2v = 0.f, d3 = 0.f;
    #pragma unroll 8
    for (int d = 0; d < DM; d += 4) {
      float4 v = *(const float4*)(row + d);
      d0 += hi[0][d] * v.x + hi[0][d + 1] * v.y + hi[0][d + 2] * v.z + hi[0][d + 3] * v.w;
      d1 += hi[1][d] * v.x + hi[1][d + 1] * v.y + hi[1][d + 2] * v.z + hi[1][d + 3] * v.w;
      d2v += hi[2][d] * v.x + hi[2][d + 1] * v.y + hi[2][d + 2] * v.z + hi[2][d + 3] * v.w;
      d3 += hi[3][d] * v.x + hi[3][d + 1] * v.y + hi[3][d + 2] * v.z + hi[3][d + 3] * v.w;
    }
    float sj = sqb[b * NN + j];
    dd[0][j] = (j == i0 + 0) ? BIGF : (sqi0 + sj - 2.f * d0);
    dd[1][j] = (j == i0 + 1) ? BIGF : (sqi1 + sj - 2.f * d1);
    dd[2][j] = (j == i0 + 2) ? BIGF : (sqi2 + sj - 2.f * d2v);
    dd[3][j] = (j == i0 + 3) ? BIGF : (sqi3 + sj - 2.f * d3);
  }
  __syncthreads();

  // phase 2: one wave per query, no block barriers
  int i = i0 + w;
  for (int it = 0; it < KNN_K; ++it) {
    float bv = BIGF; int bi = 0x3fffffff;
    for (int j = lane; j < NN; j += 64) {
      float v = dd[w][j];
      if (v < bv) { bv = v; bi = j; }
    }
    #pragma unroll
    for (int o = 1; o < 64; o <<= 1) {
      float ov = __shfl_xor(bv, o); int oi = __shfl_xor(bi, o);
      if (ov < bv || (ov == bv && oi < bi)) { bv = ov; bi = oi; }
    }
    if (lane == 0) {
      dd[w][bi] = BIGF;
      atomicOr(&adj[((size_t)b * N1 + i) * ADJW + (bi >> 6)], 1ull << (bi & 63));
      atomicOr(&adj[((size_t)b * N1 + bi) * ADJW + (i >> 6)], 1ull << (i & 63));
    }
  }
}

// ---------------------------------------------------------------- conn bitmask build
// conn(i,j) = knn | hier-band | i==0 | j==0 | i==N | j==N | i==j ; tail bits zeroed
__global__ void connb_kernel(const unsigned long long* __restrict__ adj,
                             u32* __restrict__ connb) {
  int idx = blockIdx.x * 256 + threadIdx.x;
  if (idx >= BB * N1) return;
  int b = idx / N1, i = idx % N1;
  const u32* arow = (const u32*)(adj + (size_t)(b * N1 + i) * ADJW);
  u32* crow = connb + (size_t)(b * N1 + i) * MW;
  bool allv = (i == 0 || i == NN);
  int lo = 0, hi = -1;
  if (i < NN) {
    int bs = i & ~127;
    lo = i - 11 < bs ? bs : i - 11;
    int be = bs + 127;
    hi = i + 11 > be ? be : i + 11;
  }
  for (int w = 0; w < MW; ++w) {
    u32 v;
    if (allv) {
      v = 0xffffffffu;
    } else {
      v = arow[w];
      int a = lo - 32 * w, bnd = hi - 32 * w;
      if (a < 0) a = 0; if (bnd > 31) bnd = 31;
      if (a <= bnd) v |= (0xffffffffu << a) & (0xffffffffu >> (31 - bnd));
      if (w == 0) v |= 1u;                       // depot col
      if (w == 32) v |= 1u;                      // global col (j=1024)
      int dg = i - 32 * w;
      if (dg >= 0 && dg < 32) v |= 1u << dg;     // diag
    }
    if (w == 32) v &= 1u;
    else if (w == 33) v = 0u;
    crow[w] = v;
  }
}

// ---------------------------------------------------------------- split-bf16 MFMA GEMM
// out[m][n] = act( sum_k in[m][k]*W[n][k] (+bias) ) (+res); hi*hi + hi*lo + lo*hi
#define BMT 32
#define BNT 64
#define BKT 64
#define LDKG 72

__device__ __forceinline__ void gemm_core(
    const float* __restrict__ in, const float* __restrict__ W,
    const float* __restrict__ bias, const float* __restrict__ res,
    float* __restrict__ out, int M, int Kdim, int Nout, int relu,
    int m0, int n0) {
  __shared__ __align__(16) u16 AsH[BMT][LDKG];
  __shared__ __align__(16) u16 AsL[BMT][LDKG];
  __shared__ __align__(16) u16 BsH[BNT][LDKG];
  __shared__ __align__(16) u16 BsL[BNT][LDKG];
  int t = threadIdx.x;
  int lane = t & 63, w = t >> 6;
  int wm = (w >> 1) * 16, wn = (w & 1) * 32;
  int quad = lane >> 4, r16 = lane & 15;

  f4 acc0 = {0.f, 0.f, 0.f, 0.f}, acc1 = {0.f, 0.f, 0.f, 0.f};

  int ar = t >> 3, as_ = (t & 7) * 8;     // A stage: 32 rows x 8 segs
  int br = t >> 2, bs_ = (t & 3) * 16;    // B stage: 64 rows x 4 segs

  for (int k0 = 0; k0 < Kdim; k0 += BKT) {
    {
      int m = m0 + ar;
      bf8 hb, lb;
      if (m < M) {
        const float* p = in + (size_t)m * Kdim + k0 + as_;
        #pragma unroll
        for (int q = 0; q < 8; ++q) {
          float x = p[q];
          u16 hh = f2bf(x);
          hb[q] = (short)hh;
          lb[q] = (short)f2bf(x - bf2f(hh));
        }
      } else {
        #pragma unroll
        for (int q = 0; q < 8; ++q) { hb[q] = 0; lb[q] = 0; }
      }
      *(bf8*)&AsH[ar][as_] = hb;
      *(bf8*)&AsL[ar][as_] = lb;
    }
    {
      const float* p = W + (size_t)(n0 + br) * Kdim + k0 + bs_;
      #pragma unroll
      for (int seg = 0; seg < 2; ++seg) {
        bf8 hb, lb;
        #pragma unroll
        for (int q = 0; q < 8; ++q) {
          float x = p[seg * 8 + q];
          u16 hh = f2bf(x);
          hb[q] = (short)hh;
          lb[q] = (short)f2bf(x - bf2f(hh));
        }
        *(bf8*)&BsH[br][bs_ + seg * 8] = hb;
        *(bf8*)&BsL[br][bs_ + seg * 8] = lb;
      }
    }
    __syncthreads();
    #pragma unroll
    for (int ks = 0; ks < BKT; ks += 32) {
      bf8 aH = *(const bf8*)&AsH[wm + r16][ks + quad * 8];
      bf8 aL = *(const bf8*)&AsL[wm + r16][ks + quad * 8];
      bf8 b0H = *(const bf8*)&BsH[wn + r16][ks + quad * 8];
      bf8 b0L = *(const bf8*)&BsL[wn + r16][ks + quad * 8];
      bf8 b1H = *(const bf8*)&BsH[wn + 16 + r16][ks + quad * 8];
      bf8 b1L = *(const bf8*)&BsL[wn + 16 + r16][ks + quad * 8];
      acc0 = __builtin_amdgcn_mfma_f32_16x16x32_bf16(aH, b0H, acc0, 0, 0, 0);
      acc0 = __builtin_amdgcn_mfma_f32_16x16x32_bf16(aH, b0L, acc0, 0, 0, 0);
      acc0 = __builtin_amdgcn_mfma_f32_16x16x32_bf16(aL, b0H, acc0, 0, 0, 0);
      acc1 = __builtin_amdgcn_mfma_f32_16x16x32_bf16(aH, b1H, acc1, 0, 0, 0);
      acc1 = __builtin_amdgcn_mfma_f32_16x16x32_bf16(aH, b1L, acc1, 0, 0, 0);
      acc1 = __builtin_amdgcn_mfma_f32_16x16x32_bf16(aL, b1H, acc1, 0, 0, 0);
    }
    __syncthreads();
  }

  #pragma unroll
  for (int tt = 0; tt < 2; ++tt) {
    f4 a = tt ? acc1 : acc0;
    int n = n0 + wn + tt * 16 + r16;
    #pragma unroll
    for (int reg = 0; reg < 4; ++reg) {
      int m = m0 + wm + quad * 4 + reg;   // C layout: col=lane&15, row=quad*4+reg
      if (m < M) {
        float v = a[reg];
        if (bias) v += bias[n];
        if (relu) v = fmaxf(v, 0.f);
        if (res) v += res[(size_t)m * Nout + n];
        out[(size_t)m * Nout + n] = v;
      }
    }
  }
}

__global__ __launch_bounds__(256) void gemm_kernel(
    const float* __restrict__ in, const float* __restrict__ W,
    const float* __restrict__ bias, const float* __restrict__ res,
    float* __restrict__ out, int M, int Kdim, int Nout, int relu) {
  gemm_core(in, W, bias, res, out, M, Kdim, Nout, relu,
            blockIdx.x * BMT, blockIdx.y * BNT);
}

__global__ __launch_bounds__(256) void gemm_qkv_kernel(
    const float* __restrict__ in, const float* __restrict__ Wq,
    const float* __restrict__ Wk, const float* __restrict__ Wv,
    float* __restrict__ Qo, float* __restrict__ Ko, float* __restrict__ Vo,
    int M) {
  const float* W = blockIdx.z == 0 ? Wq : (blockIdx.z == 1 ? Wk : Wv);
  float* out = blockIdx.z == 0 ? Qo : (blockIdx.z == 1 ? Ko : Vo);
  gemm_core(in, W, nullptr, nullptr, out, M, DM, DM, 0,
            blockIdx.x * BMT, blockIdx.y * BNT);
}

// ---------------------------------------------------------------- MFMA flash attention
// 2 waves/block, 16 queries/wave, 64-key chunks. QK^T exact via [hi|lo] A-operand trick.
#define CH 64
#define NCH 17
__global__ __launch_bounds__(128) void attn_kernel(
    const float* __restrict__ Q, const float* __restrict__ Kb, const float* __restrict__ Vb,
    const float* __restrict__ emb_l, const unsigned char* __restrict__ buckp,
    const u32* __restrict__ connb, float* __restrict__ ctx) {
  __shared__ __align__(16) u16 KsHi[CH][20];
  __shared__ __align__(16) u16 KsLo[CH][20];
  __shared__ __align__(16) u16 Vt[DK][68];
  __shared__ __align__(16) u16 Ps[2][16][72];
  __shared__ float qe_s[2][16][33];
  __shared__ u32 maskS[32][MW];
  __shared__ unsigned char buckS[32][68];

  int qt = blockIdx.x;                 // 0..32
  int h = blockIdx.y, b = blockIdx.z;
  int t = threadIdx.x, lane = t & 63, w = t >> 6;
  int quad = lane >> 4, r16 = lane & 15;
  int i0 = qt * 32;
  int iw = i0 + w * 16;

  // stage mask words for this block's 32 rows
  for (int x = t; x < 32 * MW; x += 128) {
    int rr = x / MW, ww = x % MW;
    int gi = i0 + rr; if (gi > NN) gi = NN;
    maskS[rr][ww] = connb[((size_t)b * N1 + gi) * MW + ww];
  }
  // qe table (fp32): wave's 16 rows x 32 buckets
  for (int e = lane; e < 512; e += 64) {
    int rr = e >> 5, bk = e & 31;
    int gi = iw + rr; if (gi > NN) gi = NN;
    const float* qrow = Q + ((size_t)b * N1 + gi) * DM + h * DK;
    const float* er = emb_l + (size_t)bk * DM + h * DK;
    float s = 0.f;
    #pragma unroll
    for (int d = 0; d < DK; ++d) s += qrow[d] * er[d];
    qe_s[w][rr][bk] = s;
  }
  // Q A-fragment: quads 0,1 = hi(0.25*Q), quads 2,3 = lo residual
  bf8 qfrag;
  {
    int gi = iw + r16; if (gi > NN) gi = NN;
    const float* qp = Q + ((size_t)b * N1 + gi) * DM + h * DK + (quad & 1) * 8;
    #pragma unroll
    for (int jj = 0; jj < 8; ++jj) {
      float x = qp[jj] * 0.25f;
      u16 hh = f2bf(x);
      qfrag[jj] = (quad < 2) ? (short)hh : (short)f2bf(x - bf2f(hh));
    }
  }
  __syncthreads();

  f4 Oacc = {0.f, 0.f, 0.f, 0.f};
  float mrun[4] = {-1e30f, -1e30f, -1e30f, -1e30f};
  float lrun[4] = {0.f, 0.f, 0.f, 0.f};

  for (int c = 0; c < NCH; ++c) {
    int j0 = c * CH;
    __syncthreads();
    // stage K hi/lo + V^T (bf16) : 64 keys x 16 d
    for (int x = t; x < 256; x += 128) {
      int key = x >> 2, ds = (x & 3) * 4;
      int jg = j0 + key; if (jg > NN) jg = NN;
      const float* kr = Kb + ((size_t)b * N1 + jg) * DM + h * DK + ds;
      const float* vr = Vb + ((size_t)b * N1 + jg) * DM + h * DK + ds;
      float4 kv = *(const float4*)kr;
      float4 vv = *(const float4*)vr;
      float ka[4] = {kv.x, kv.y, kv.z, kv.w};
      ushort4 hbuf, lbuf;
      u16* hp = (u16*)&hbuf; u16* lp = (u16*)&lbuf;
      #pragma unroll
      for (int q = 0; q < 4; ++q) {
        u16 hh = f2bf(ka[q]);
        hp[q] = hh;
        lp[q] = f2bf(ka[q] - bf2f(hh));
      }
      *(ushort4*)&KsHi[key][ds] = hbuf;
      *(ushort4*)&KsLo[key][ds] = lbuf;
      Vt[ds + 0][key] = f2bf(vv.x);
      Vt[ds + 1][key] = f2bf(vv.y);
      Vt[ds + 2][key] = f2bf(vv.z);
      Vt[ds + 3][key] = f2bf(vv.w);
    }
    // stage bucket bytes: 32 rows x 64 cols
    for (int x = t; x < 512; x += 128) {
      int rr = x >> 4, c4 = (x & 15) * 4;
      int gi = i0 + rr; if (gi > NN) gi = NN;
      u32 bv = *(const u32*)(buckp + ((size_t)b * N1 + gi) * BSTR + j0 + c4);
      *(u32*)&buckS[rr][c4] = bv;
    }
    __syncthreads();

    // QK^T: 4 tiles of 16 keys, exact product via two MFMAs
    f4 S[4];
    #pragma unroll
    for (int tt = 0; tt < 4; ++tt) {
      int key = tt * 16 + r16;
      int off = (quad & 1) * 8;
      bf8 bh = mk8(*(const ushort4*)&KsHi[key][off], *(const ushort4*)&KsHi[key][off + 4]);
      bf8 bl = mk8(*(const ushort4*)&KsLo[key][off], *(const ushort4*)&KsLo[key][off + 4]);
      f4 z = {0.f, 0.f, 0.f, 0.f};
      z = __builtin_amdgcn_mfma_f32_16x16x32_bf16(qfrag, bh, z, 0, 0, 0);
      z = __builtin_amdgcn_mfma_f32_16x16x32_bf16(qfrag, bl, z, 0, 0, 0);
      S[tt] = z;
    }

    // rel + mask + online softmax
    float sv[4][4];
    #pragma unroll
    for (int rg = 0; rg < 4; ++rg) {
      int rowb = w * 16 + quad * 4 + rg;
      u32 mw0 = maskS[rowb][2 * c];
      u32 mw1 = maskS[rowb][2 * c + 1];
      #pragma unroll
      for (int tt = 0; tt < 4; ++tt) {
        u32 mword = (tt & 2) ? mw1 : mw0;
        int bit = (tt & 1) * 16 + r16;
        int bk = buckS[rowb][tt * 16 + r16] & 31;
        float rel = qe_s[w][quad * 4 + rg][bk];
        float s = S[tt][rg] + rel;
        s += ((mword >> bit) & 1u) ? 0.f : -1.0e9f;
        sv[rg][tt] = s;
      }
    }
    #pragma unroll
    for (int rg = 0; rg < 4; ++rg) {
      float tm = fmaxf(fmaxf(sv[rg][0], sv[rg][1]), fmaxf(sv[rg][2], sv[rg][3]));
      #pragma unroll
      for (int o = 1; o < 16; o <<= 1) tm = fmaxf(tm, __shfl_xor(tm, o));
      float nm = fmaxf(mrun[rg], tm);
      float al = __expf(mrun[rg] - nm);
      mrun[rg] = nm;
      float ps = 0.f;
      #pragma unroll
      for (int tt = 0; tt < 4; ++tt) {
        float p = __expf(sv[rg][tt] - nm);
        ps += p;
        Ps[w][quad * 4 + rg][tt * 16 + r16] = f2bf(p);
      }
      #pragma unroll
      for (int o = 1; o < 16; o <<= 1) ps += __shfl_xor(ps, o);
      lrun[rg] = lrun[rg] * al + ps;
      Oacc[rg] *= al;
    }
    // PV: P (A-layout via LDS round trip) x V^T, k=32 fully used
    #pragma unroll
    for (int half = 0; half < 2; ++half) {
      bf8 pa = *(const bf8*)&Ps[w][r16][half * 32 + quad * 8];
      bf8 vb = mk8(*(const ushort4*)&Vt[r16][half * 32 + quad * 8],
                   *(const ushort4*)&Vt[r16][half * 32 + quad * 8 + 4]);
      Oacc = __builtin_amdgcn_mfma_f32_16x16x32_bf16(pa, vb, Oacc, 0, 0, 0);
    }
  }

  #pragma unroll
  for (int rg = 0; rg < 4; ++rg) {
    int gi = i0 + w * 16 + quad * 4 + rg;
    if (gi < N1)
      ctx[((size_t)b * N1 + gi) * DM + h * DK + r16] = Oacc[rg] / lrun[rg];
  }
}

// ---------------------------------------------------------------- instance norm (+pool, +g-update)
__global__ void inorm_kernel(float* __restrict__ X, const float* __restrict__ w,
                             const float* __restrict__ b_, float* __restrict__ pool,
                             int do_g) {
  int d = blockIdx.x; int bb = blockIdx.y; int lane = threadIdx.x;  // 64 threads
  float g_old = X[((size_t)bb * N1 + NN) * DM + d];
  float s = 0.f;
  for (int n = lane; n < N1; n += 64) s += X[((size_t)bb * N1 + n) * DM + d];
  #pragma unroll
  for (int o = 1; o < 64; o <<= 1) s += __shfl_xor(s, o);
  float mu = s * (1.0f / N1);
  float v = 0.f;
  for (int n = lane; n < N1; n += 64) {
    float tt = X[((size_t)bb * N1 + n) * DM + d] - mu;
    v += tt * tt;
  }
  #pragma unroll
  for (int o = 1; o < 64; o <<= 1) v += __shfl_xor(v, o);
  float var = v * (1.0f / N1);
  float scv = rsqrtf(var + 1e-5f) * w[d];
  float sh = b_[d];
  for (int n = lane; n < N1; n += 64) {
    size_t id = ((size_t)bb * N1 + n) * DM + d;
    X[id] = (X[id] - mu) * scv + sh;
  }
  if (lane == 0) {
    float hmean = ((s - g_old) * (1.0f / NN) - mu) * scv + sh;
    if (pool) pool[bb * DM + d] = hmean;
    if (do_g) X[((size_t)bb * N1 + NN) * DM + d] += hmean;
  }
}

// ---------------------------------------------------------------- p_multi
__global__ void pmulti_kernel(const float* __restrict__ pools, float* __restrict__ pm,
                              float* __restrict__ out_pm) {
  int idx = blockIdx.x * 64 + threadIdx.x;
  if (idx >= BB * DM) return;
  float v = (pools[idx] + pools[BB * DM + idx] + pools[2 * BB * DM + idx]) * (1.0f / 3.0f);
  pm[idx] = v;
  out_pm[idx] = v;
}

// ---------------------------------------------------------------- tmp = h + p_multi
__global__ void addpm_kernel(const float* __restrict__ X, const float* __restrict__ pm,
                             float* __restrict__ tmp) {
  int idx = blockIdx.x * 256 + threadIdx.x;
  if (idx >= BB * NN * DM) return;
  int d = idx % DM; int n = (idx / DM) % NN; int b = idx / (DM * NN);
  tmp[idx] = X[((size_t)b * N1 + n) * DM + d] + pm[b * DM + d];
}

// ================================================================ launch
extern "C" void kernel_launch(void* const* d_in, const int* in_sizes, int n_in,
                              void* d_out, int out_size, void* d_ws, size_t ws_size,
                              hipStream_t stream) {
  const float* coords = (const float*)d_in[0];
  const float* inW    = (const float*)d_in[1];
  const float* inb    = (const float*)d_in[2];
  const float* gnode  = (const float*)d_in[3];
  const float* Wq     = (const float*)d_in[4];
  const float* Wk     = (const float*)d_in[5];
  const float* Wv     = (const float*)d_in[6];
  const float* Wo     = (const float*)d_in[7];
  const float* emb    = (const float*)d_in[8];
  const float* W1     = (const float*)d_in[9];
  const float* b1     = (const float*)d_in[10];
  const float* W2     = (const float*)d_in[11];
  const float* b2     = (const float*)d_in[12];
  const float* n1w    = (const float*)d_in[13];
  const float* n1b    = (const float*)d_in[14];
  const float* n2w    = (const float*)d_in[15];
  const float* n2b    = (const float*)d_in[16];
  const float* outW   = (const float*)d_in[17];
  const float* outb   = (const float*)d_in[18];
  float* out = (float*)d_out;

  char* wsp = (char*)d_ws;
  size_t off = 0;
  auto alloc = [&](size_t bytes) -> void* {
    off = (off + 255) & ~(size_t)255;
    void* p = wsp + off;
    off += bytes;
    return p;
  };
  const size_t XB = (size_t)BB * N1 * DM * 4;
  float* X0   = (float*)alloc(XB);
  float* X1   = (float*)alloc(XB);
  float* Qb   = (float*)alloc(XB);
  float* Kbuf = (float*)alloc(XB);
  float* Vbuf = (float*)alloc(XB);
  float* Cb   = (float*)alloc(XB);
  float* Yb   = (float*)alloc(XB);
  float* Fb   = (float*)alloc((size_t)BB * N1 * DFF * 4);
  unsigned char* buckp = (unsigned char*)alloc((size_t)BB * N1 * BSTR);
  unsigned long long* adj = (unsigned long long*)alloc((size_t)BB * N1 * ADJW * 8);
  u32* connb = (u32*)alloc((size_t)BB * N1 * MW * 4);
  float* sqb   = (float*)alloc((size_t)BB * NN * 4);
  float* pools = (float*)alloc((size_t)NLAYERS * BB * DM * 4);
  float* pm    = (float*)alloc((size_t)BB * DM * 4);
  float* tmp   = (float*)alloc((size_t)BB * NN * DM * 4);

  embed_kernel<<<(BB * N1 * DM + 255) / 256, 256, 0, stream>>>(coords, inW, inb, gnode, X0);
  bucket_kernel<<<(BB * N1 * BSTR + 255) / 256, 256, 0, stream>>>(coords, buckp);
  g_update_kernel<<<dim3(DM, BB), 64, 0, stream>>>(X0);   // layer 0 g-update

  float* Xin = X0; float* Xout = X1;
  const int M = BB * N1;
  const int GM = (M + BMT - 1) / BMT;   // 65
  for (int l = 0; l < NLAYERS; ++l) {
    hipMemsetAsync(adj, 0, (size_t)BB * N1 * ADJW * 8, stream);
    rowsq_kernel<<<(BB * NN + 63) / 64, 64, 0, stream>>>(Xin, sqb);
    knn_kernel<<<BB * NN / 4, 256, 0, stream>>>(Xin, sqb, adj);
    connb_kernel<<<(BB * N1 + 255) / 256, 256, 0, stream>>>(adj, connb);

    gemm_qkv_kernel<<<dim3(GM, DM / BNT, 3), 256, 0, stream>>>(
        Xin, Wq + (size_t)l * DM * DM, Wk + (size_t)l * DM * DM, Wv + (size_t)l * DM * DM,
        Qb, Kbuf, Vbuf, M);

    attn_kernel<<<dim3(33, NH, BB), 128, 0, stream>>>(
        Qb, Kbuf, Vbuf, emb + (size_t)l * NBUK * DM, buckp, connb, Cb);

    gemm_kernel<<<dim3(GM, DM / BNT), 256, 0, stream>>>(
        Cb, Wo + (size_t)l * DM * DM, nullptr, Xin, Yb, M, DM, DM, 0);
    inorm_kernel<<<dim3(DM, BB), 64, 0, stream>>>(Yb, n1w + l * DM, n1b + l * DM, nullptr, 0);

    gemm_kernel<<<dim3(GM, DFF / BNT), 256, 0, stream>>>(
        Yb, W1 + (size_t)l * DFF * DM, b1 + l * DFF, nullptr, Fb, M, DM, DFF, 1);
    gemm_kernel<<<dim3(GM, DM / BNT), 256, 0, stream>>>(
        Fb, W2 + (size_t)l * DM * DFF, b2 + l * DM, Yb, Xout, M, DFF, DM, 0);
    // fused: inorm + pool + g-update for next layer
    inorm_kernel<<<dim3(DM, BB), 64, 0, stream>>>(Xout, n2w + l * DM, n2b + l * DM,
                                                  pools + (size_t)l * BB * DM, 1);

    float* t2 = Xin; Xin = Xout; Xout = t2;
  }

  pmulti_kernel<<<(BB * DM + 63) / 64, 64, 0, stream>>>(pools, pm, out + (size_t)BB * NN * DM);
  addpm_kernel<<<(BB * NN * DM + 255) / 256, 256, 0, stream>>>(Xin, pm, tmp);
  gemm_kernel<<<dim3((BB * NN + BMT - 1) / BMT, DM / BNT), 256, 0, stream>>>(
      tmp, outW, outb, nullptr, out, BB * NN, DM, DM, 0);
}

// Round 4
// 649.886 us; speedup vs baseline: 2.4552x; 1.0800x over previous
//
#include <hip/hip_runtime.h>

#define BB 2
#define NN 1024
#define N1 1025
#define DM 128
#define NH 8
#define DK 16
#define DFF 512
#define NBUK 32
#define NLAYERS 3
#define KNN_K 10
#define ADJW 17          // 1025 bits -> 17 u64 words per row
#define MW 34            // 34 u32 mask words per row (1088 bits)
#define BSTR 1088        // padded bucket row stride (bytes)
#define NSPLIT 4
#define BIGF 3.0e38f

typedef __attribute__((ext_vector_type(8))) short bf8;
typedef __attribute__((ext_vector_type(4))) float f4;
typedef unsigned short u16;
typedef unsigned int u32;

__device__ __forceinline__ u16 f2bf(float x) {
  unsigned u = __float_as_uint(x);
  return (u16)((u + 0x7fff + ((u >> 16) & 1)) >> 16);   // RNE
}
__device__ __forceinline__ float bf2f(u16 u) {
  return __uint_as_float(((unsigned)u) << 16);
}
__device__ __forceinline__ bf8 mk8(ushort4 a, ushort4 b) {
  bf8 r;
  r[0] = (short)a.x; r[1] = (short)a.y; r[2] = (short)a.z; r[3] = (short)a.w;
  r[4] = (short)b.x; r[5] = (short)b.y; r[6] = (short)b.z; r[7] = (short)b.w;
  return r;
}

// ---------------------------------------------------------------- embed
__global__ void embed_kernel(const float* __restrict__ coords, const float* __restrict__ inW,
                             const float* __restrict__ inb, const float* __restrict__ gnode,
                             float* __restrict__ X) {
  int idx = blockIdx.x * 256 + threadIdx.x;
  if (idx >= BB * N1 * DM) return;
  int d = idx % DM; int r = idx / DM; int n = r % N1; int b = r / N1;
  float v;
  if (n < NN) {
    float cx = coords[(b * NN + n) * 2 + 0], cy = coords[(b * NN + n) * 2 + 1];
    v = cx * inW[d * 2 + 0] + cy * inW[d * 2 + 1] + inb[d];
  } else {
    v = gnode[d];
  }
  X[idx] = v;
}

// ---------------------------------------------------------------- bucket (padded rows)
__global__ void bucket_kernel(const float* __restrict__ coords, unsigned char* __restrict__ buckp) {
  int idx = blockIdx.x * 256 + threadIdx.x;
  if (idx >= BB * N1 * BSTR) return;
  int j = idx % BSTR; int r = idx / BSTR; int i = r % N1; int b = r / N1;
  unsigned char v = 0;
  if (j < N1) {
    float xi = 0.f, yi = 0.f, xj = 0.f, yj = 0.f;
    if (i < NN) { xi = coords[(b * NN + i) * 2]; yi = coords[(b * NN + i) * 2 + 1]; }
    if (j < NN) { xj = coords[(b * NN + j) * 2]; yj = coords[(b * NN + j) * 2 + 1]; }
    float dx = xi - xj, dy = yi - yj;
    float dist = sqrtf(dx * dx + dy * dy);
    int bu = (int)(dist * 32.0f);
    bu = bu < 0 ? 0 : (bu > 31 ? 31 : bu);
    v = (unsigned char)bu;
  }
  buckp[idx] = v;
}

// ---------------------------------------------------------------- g += mean(h) (layer 0 only)
__global__ void g_update_kernel(float* __restrict__ X) {
  int d = blockIdx.x; int b = blockIdx.y; int lane = threadIdx.x;  // 64 threads
  float s = 0.f;
  for (int n = lane; n < NN; n += 64) s += X[((size_t)b * N1 + n) * DM + d];
  for (int o = 32; o; o >>= 1) s += __shfl_down(s, o);
  if (lane == 0) X[((size_t)b * N1 + NN) * DM + d] += s * (1.0f / NN);
}

// ---------------------------------------------------------------- row squared norms
__global__ void rowsq_kernel(const float* __restrict__ X, float* __restrict__ sq) {
  int idx = blockIdx.x * 64 + threadIdx.x;
  if (idx >= BB * NN) return;
  int n = idx % NN, b = idx / NN;
  const float* row = X + ((size_t)b * N1 + n) * DM;
  float s = 0.f;
  #pragma unroll 8
  for (int d = 0; d < DM; d += 4) {
    float4 v = *(const float4*)(row + d);
    s += v.x * v.x + v.y * v.y + v.z * v.z + v.w * v.w;
  }
  sq[idx] = s;
}

// ---------------------------------------------------------------- kNN -> adjacency bits
__global__ __launch_bounds__(256) void knn_kernel(const float* __restrict__ X,
                                                  const float* __restrict__ sqb,
                                                  unsigned long long* __restrict__ adj) {
  __shared__ float hi[4][DM];
  __shared__ float dd[4][NN];
  int blk = blockIdx.x;
  int b = blk / (NN / 4);
  int i0 = (blk % (NN / 4)) * 4;
  int t = threadIdx.x;
  int lane = t & 63, w = t >> 6;

  for (int x = t; x < 4 * DM; x += 256)
    hi[x >> 7][x & 127] = X[((size_t)b * N1 + i0 + (x >> 7)) * DM + (x & 127)];
  __syncthreads();

  float sqi0 = sqb[b * NN + i0 + 0];
  float sqi1 = sqb[b * NN + i0 + 1];
  float sqi2 = sqb[b * NN + i0 + 2];
  float sqi3 = sqb[b * NN + i0 + 3];

  for (int j = t; j < NN; j += 256) {
    const float* row = X + ((size_t)b * N1 + j) * DM;
    float d0 = 0.f, d1 = 0.f, d2v = 0.f, d3 = 0.f;
    #pragma unroll 8
    for (int d = 0; d < DM; d += 4) {
      float4 v = *(const float4*)(row + d);
      d0 += hi[0][d] * v.x + hi[0][d + 1] * v.y + hi[0][d + 2] * v.z + hi[0][d + 3] * v.w;
      d1 += hi[1][d] * v.x + hi[1][d + 1] * v.y + hi[1][d + 2] * v.z + hi[1][d + 3] * v.w;
      d2v += hi[2][d] * v.x + hi[2][d + 1] * v.y + hi[2][d + 2] * v.z + hi[2][d + 3] * v.w;
      d3 += hi[3][d] * v.x + hi[3][d + 1] * v.y + hi[3][d + 2] * v.z + hi[3][d + 3] * v.w;
    }
    float sj = sqb[b * NN + j];
    dd[0][j] = (j == i0 + 0) ? BIGF : (sqi0 + sj - 2.f * d0);
    dd[1][j] = (j == i0 + 1) ? BIGF : (sqi1 + sj - 2.f * d1);
    dd[2][j] = (j == i0 + 2) ? BIGF : (sqi2 + sj - 2.f * d2v);
    dd[3][j] = (j == i0 + 3) ? BIGF : (sqi3 + sj - 2.f * d3);
  }
  __syncthreads();

  // phase 2: one wave per query, no block barriers
  int i = i0 + w;
  for (int it = 0; it < KNN_K; ++it) {
    float bv = BIGF; int bi = 0x3fffffff;
    for (int j = lane; j < NN; j += 64) {
      float v = dd[w][j];
      if (v < bv) { bv = v; bi = j; }
    }
    #pragma unroll
    for (int o = 1; o < 64; o <<= 1) {
      float ov = __shfl_xor(bv, o); int oi = __shfl_xor(bi, o);
      if (ov < bv || (ov == bv && oi < bi)) { bv = ov; bi = oi; }
    }
    if (lane == 0) {
      dd[w][bi] = BIGF;
      atomicOr(&adj[((size_t)b * N1 + i) * ADJW + (bi >> 6)], 1ull << (bi & 63));
      atomicOr(&adj[((size_t)b * N1 + bi) * ADJW + (i >> 6)], 1ull << (i & 63));
    }
  }
}

// ---------------------------------------------------------------- conn bitmask build
__global__ void connb_kernel(const unsigned long long* __restrict__ adj,
                             u32* __restrict__ connb) {
  int idx = blockIdx.x * 256 + threadIdx.x;
  if (idx >= BB * N1) return;
  int b = idx / N1, i = idx % N1;
  const u32* arow = (const u32*)(adj + (size_t)(b * N1 + i) * ADJW);
  u32* crow = connb + (size_t)(b * N1 + i) * MW;
  bool allv = (i == 0 || i == NN);
  int lo = 0, hi = -1;
  if (i < NN) {
    int bs = i & ~127;
    lo = i - 11 < bs ? bs : i - 11;
    int be = bs + 127;
    hi = i + 11 > be ? be : i + 11;
  }
  for (int w = 0; w < MW; ++w) {
    u32 v;
    if (allv) {
      v = 0xffffffffu;
    } else {
      v = arow[w];
      int a = lo - 32 * w, bnd = hi - 32 * w;
      if (a < 0) a = 0; if (bnd > 31) bnd = 31;
      if (a <= bnd) v |= (0xffffffffu << a) & (0xffffffffu >> (31 - bnd));
      if (w == 0) v |= 1u;                       // depot col
      if (w == 32) v |= 1u;                      // global col (j=1024)
      int dg = i - 32 * w;
      if (dg >= 0 && dg < 32) v |= 1u << dg;     // diag
    }
    if (w == 32) v &= 1u;
    else if (w == 33) v = 0u;
    crow[w] = v;
  }
}

// ---------------------------------------------------------------- split-bf16 MFMA GEMM
#define BMT 32
#define BNT 64
#define BKT 64
#define LDKG 72

__device__ __forceinline__ void gemm_core(
    const float* __restrict__ in, const float* __restrict__ W,
    const float* __restrict__ bias, const float* __restrict__ res,
    float* __restrict__ out, int M, int Kdim, int Nout, int relu,
    int m0, int n0) {
  __shared__ __align__(16) u16 AsH[BMT][LDKG];
  __shared__ __align__(16) u16 AsL[BMT][LDKG];
  __shared__ __align__(16) u16 BsH[BNT][LDKG];
  __shared__ __align__(16) u16 BsL[BNT][LDKG];
  int t = threadIdx.x;
  int lane = t & 63, w = t >> 6;
  int wm = (w >> 1) * 16, wn = (w & 1) * 32;
  int quad = lane >> 4, r16 = lane & 15;

  f4 acc0 = {0.f, 0.f, 0.f, 0.f}, acc1 = {0.f, 0.f, 0.f, 0.f};

  int ar = t >> 3, as_ = (t & 7) * 8;     // A stage: 32 rows x 8 segs
  int br = t >> 2, bs_ = (t & 3) * 16;    // B stage: 64 rows x 4 segs

  for (int k0 = 0; k0 < Kdim; k0 += BKT) {
    {
      int m = m0 + ar;
      bf8 hb, lb;
      if (m < M) {
        const float* p = in + (size_t)m * Kdim + k0 + as_;
        #pragma unroll
        for (int q = 0; q < 8; ++q) {
          float x = p[q];
          u16 hh = f2bf(x);
          hb[q] = (short)hh;
          lb[q] = (short)f2bf(x - bf2f(hh));
        }
      } else {
        #pragma unroll
        for (int q = 0; q < 8; ++q) { hb[q] = 0; lb[q] = 0; }
      }
      *(bf8*)&AsH[ar][as_] = hb;
      *(bf8*)&AsL[ar][as_] = lb;
    }
    {
      const float* p = W + (size_t)(n0 + br) * Kdim + k0 + bs_;
      #pragma unroll
      for (int seg = 0; seg < 2; ++seg) {
        bf8 hb, lb;
        #pragma unroll
        for (int q = 0; q < 8; ++q) {
          float x = p[seg * 8 + q];
          u16 hh = f2bf(x);
          hb[q] = (short)hh;
          lb[q] = (short)f2bf(x - bf2f(hh));
        }
        *(bf8*)&BsH[br][bs_ + seg * 8] = hb;
        *(bf8*)&BsL[br][bs_ + seg * 8] = lb;
      }
    }
    __syncthreads();
    #pragma unroll
    for (int ks = 0; ks < BKT; ks += 32) {
      bf8 aH = *(const bf8*)&AsH[wm + r16][ks + quad * 8];
      bf8 aL = *(const bf8*)&AsL[wm + r16][ks + quad * 8];
      bf8 b0H = *(const bf8*)&BsH[wn + r16][ks + quad * 8];
      bf8 b0L = *(const bf8*)&BsL[wn + r16][ks + quad * 8];
      bf8 b1H = *(const bf8*)&BsH[wn + 16 + r16][ks + quad * 8];
      bf8 b1L = *(const bf8*)&BsL[wn + 16 + r16][ks + quad * 8];
      acc0 = __builtin_amdgcn_mfma_f32_16x16x32_bf16(aH, b0H, acc0, 0, 0, 0);
      acc0 = __builtin_amdgcn_mfma_f32_16x16x32_bf16(aH, b0L, acc0, 0, 0, 0);
      acc0 = __builtin_amdgcn_mfma_f32_16x16x32_bf16(aL, b0H, acc0, 0, 0, 0);
      acc1 = __builtin_amdgcn_mfma_f32_16x16x32_bf16(aH, b1H, acc1, 0, 0, 0);
      acc1 = __builtin_amdgcn_mfma_f32_16x16x32_bf16(aH, b1L, acc1, 0, 0, 0);
      acc1 = __builtin_amdgcn_mfma_f32_16x16x32_bf16(aL, b1H, acc1, 0, 0, 0);
    }
    __syncthreads();
  }

  #pragma unroll
  for (int tt = 0; tt < 2; ++tt) {
    f4 a = tt ? acc1 : acc0;
    int n = n0 + wn + tt * 16 + r16;
    #pragma unroll
    for (int reg = 0; reg < 4; ++reg) {
      int m = m0 + wm + quad * 4 + reg;   // C layout: col=lane&15, row=quad*4+reg
      if (m < M) {
        float v = a[reg];
        if (bias) v += bias[n];
        if (relu) v = fmaxf(v, 0.f);
        if (res) v += res[(size_t)m * Nout + n];
        out[(size_t)m * Nout + n] = v;
      }
    }
  }
}

__global__ __launch_bounds__(256) void gemm_kernel(
    const float* __restrict__ in, const float* __restrict__ W,
    const float* __restrict__ bias, const float* __restrict__ res,
    float* __restrict__ out, int M, int Kdim, int Nout, int relu) {
  gemm_core(in, W, bias, res, out, M, Kdim, Nout, relu,
            blockIdx.x * BMT, blockIdx.y * BNT);
}

__global__ __launch_bounds__(256) void gemm_qkv_kernel(
    const float* __restrict__ in, const float* __restrict__ Wq,
    const float* __restrict__ Wk, const float* __restrict__ Wv,
    float* __restrict__ Qo, float* __restrict__ Ko, float* __restrict__ Vo,
    int M) {
  const float* W = blockIdx.z == 0 ? Wq : (blockIdx.z == 1 ? Wk : Wv);
  float* out = blockIdx.z == 0 ? Qo : (blockIdx.z == 1 ? Ko : Vo);
  gemm_core(in, W, nullptr, nullptr, out, M, DM, DM, 0,
            blockIdx.x * BMT, blockIdx.y * BNT);
}

// ---------------------------------------------------------------- MFMA flash attention, key-split
// 2 waves/block, 16 queries/wave, 64-key chunks; NSPLIT blocks cover disjoint chunk ranges
// and emit unnormalized partials (O, m, l) combined by attn_combine_kernel.
#define CH 64
#define NCH 17
__global__ __launch_bounds__(128) void attn_kernel(
    const float* __restrict__ Q, const float* __restrict__ Kb, const float* __restrict__ Vb,
    const float* __restrict__ emb_l, const unsigned char* __restrict__ buckp,
    const u32* __restrict__ connb, float* __restrict__ Opart,
    float* __restrict__ mpart, float* __restrict__ lpart) {
  __shared__ __align__(16) u16 KsHi[CH][20];
  __shared__ __align__(16) u16 KsLo[CH][20];
  __shared__ __align__(16) u16 Vt[DK][68];
  __shared__ __align__(16) u16 Ps[2][16][72];
  __shared__ float qe_s[2][16][33];
  __shared__ u32 maskS[32][10];
  __shared__ unsigned char buckS[32][68];

  int qt = blockIdx.x;                 // 0..32
  int h = blockIdx.y & 7, b = blockIdx.y >> 3;
  int s = blockIdx.z;
  int c0 = (NCH * s) / NSPLIT, c1 = (NCH * (s + 1)) / NSPLIT;
  int nw = 2 * (c1 - c0);
  int t = threadIdx.x, lane = t & 63, w = t >> 6;
  int quad = lane >> 4, r16 = lane & 15;
  int i0 = qt * 32;
  int iw = i0 + w * 16;
  int bh = b * NH + h;

  // stage this split's mask words for the block's 32 rows
  for (int x = t; x < 32 * nw; x += 128) {
    int rr = x / nw, ww = x % nw;
    int gi = i0 + rr; if (gi > NN) gi = NN;
    maskS[rr][ww] = connb[((size_t)b * N1 + gi) * MW + 2 * c0 + ww];
  }
  // qe table (fp32): wave's 16 rows x 32 buckets
  for (int e = lane; e < 512; e += 64) {
    int rr = e >> 5, bk = e & 31;
    int gi = iw + rr; if (gi > NN) gi = NN;
    const float* qrow = Q + ((size_t)b * N1 + gi) * DM + h * DK;
    const float* er = emb_l + (size_t)bk * DM + h * DK;
    float sum = 0.f;
    #pragma unroll
    for (int d = 0; d < DK; ++d) sum += qrow[d] * er[d];
    qe_s[w][rr][bk] = sum;
  }
  // Q A-fragment: quads 0,1 = hi(0.25*Q), quads 2,3 = lo residual
  bf8 qfrag;
  {
    int gi = iw + r16; if (gi > NN) gi = NN;
    const float* qp = Q + ((size_t)b * N1 + gi) * DM + h * DK + (quad & 1) * 8;
    #pragma unroll
    for (int jj = 0; jj < 8; ++jj) {
      float x = qp[jj] * 0.25f;
      u16 hh = f2bf(x);
      qfrag[jj] = (quad < 2) ? (short)hh : (short)f2bf(x - bf2f(hh));
    }
  }
  __syncthreads();

  f4 Oacc = {0.f, 0.f, 0.f, 0.f};
  float mrun[4] = {-1e30f, -1e30f, -1e30f, -1e30f};
  float lrun[4] = {0.f, 0.f, 0.f, 0.f};

  for (int c = c0; c < c1; ++c) {
    int j0 = c * CH;
    __syncthreads();
    // stage K hi/lo + V^T (bf16) : 64 keys x 16 d
    for (int x = t; x < 256; x += 128) {
      int key = x >> 2, ds = (x & 3) * 4;
      int jg = j0 + key; if (jg > NN) jg = NN;
      const float* kr = Kb + ((size_t)b * N1 + jg) * DM + h * DK + ds;
      const float* vr = Vb + ((size_t)b * N1 + jg) * DM + h * DK + ds;
      float4 kv = *(const float4*)kr;
      float4 vv = *(const float4*)vr;
      float ka[4] = {kv.x, kv.y, kv.z, kv.w};
      ushort4 hbuf, lbuf;
      u16* hp = (u16*)&hbuf; u16* lp = (u16*)&lbuf;
      #pragma unroll
      for (int q = 0; q < 4; ++q) {
        u16 hh = f2bf(ka[q]);
        hp[q] = hh;
        lp[q] = f2bf(ka[q] - bf2f(hh));
      }
      *(ushort4*)&KsHi[key][ds] = hbuf;
      *(ushort4*)&KsLo[key][ds] = lbuf;
      Vt[ds + 0][key] = f2bf(vv.x);
      Vt[ds + 1][key] = f2bf(vv.y);
      Vt[ds + 2][key] = f2bf(vv.z);
      Vt[ds + 3][key] = f2bf(vv.w);
    }
    // stage bucket bytes: 32 rows x 64 cols
    for (int x = t; x < 512; x += 128) {
      int rr = x >> 4, c4 = (x & 15) * 4;
      int gi = i0 + rr; if (gi > NN) gi = NN;
      u32 bv = *(const u32*)(buckp + ((size_t)b * N1 + gi) * BSTR + j0 + c4);
      *(u32*)&buckS[rr][c4] = bv;
    }
    __syncthreads();

    // QK^T: 4 tiles of 16 keys, exact product via two MFMAs
    f4 S[4];
    #pragma unroll
    for (int tt = 0; tt < 4; ++tt) {
      int key = tt * 16 + r16;
      int off = (quad & 1) * 8;
      bf8 bhv = mk8(*(const ushort4*)&KsHi[key][off], *(const ushort4*)&KsHi[key][off + 4]);
      bf8 blv = mk8(*(const ushort4*)&KsLo[key][off], *(const ushort4*)&KsLo[key][off + 4]);
      f4 z = {0.f, 0.f, 0.f, 0.f};
      z = __builtin_amdgcn_mfma_f32_16x16x32_bf16(qfrag, bhv, z, 0, 0, 0);
      z = __builtin_amdgcn_mfma_f32_16x16x32_bf16(qfrag, blv, z, 0, 0, 0);
      S[tt] = z;
    }

    // rel + mask + online softmax
    float sv[4][4];
    #pragma unroll
    for (int rg = 0; rg < 4; ++rg) {
      int rowb = w * 16 + quad * 4 + rg;
      u32 mw0 = maskS[rowb][2 * (c - c0)];
      u32 mw1 = maskS[rowb][2 * (c - c0) + 1];
      #pragma unroll
      for (int tt = 0; tt < 4; ++tt) {
        u32 mword = (tt & 2) ? mw1 : mw0;
        int bit = (tt & 1) * 16 + r16;
        int bk = buckS[rowb][tt * 16 + r16] & 31;
        float rel = qe_s[w][quad * 4 + rg][bk];
        float sc = S[tt][rg] + rel;
        sc += ((mword >> bit) & 1u) ? 0.f : -1.0e9f;
        sv[rg][tt] = sc;
      }
    }
    #pragma unroll
    for (int rg = 0; rg < 4; ++rg) {
      float tm = fmaxf(fmaxf(sv[rg][0], sv[rg][1]), fmaxf(sv[rg][2], sv[rg][3]));
      #pragma unroll
      for (int o = 1; o < 16; o <<= 1) tm = fmaxf(tm, __shfl_xor(tm, o));
      float nm = fmaxf(mrun[rg], tm);
      float al = __expf(mrun[rg] - nm);
      mrun[rg] = nm;
      float ps = 0.f;
      #pragma unroll
      for (int tt = 0; tt < 4; ++tt) {
        float p = __expf(sv[rg][tt] - nm);
        ps += p;
        Ps[w][quad * 4 + rg][tt * 16 + r16] = f2bf(p);
      }
      #pragma unroll
      for (int o = 1; o < 16; o <<= 1) ps += __shfl_xor(ps, o);
      lrun[rg] = lrun[rg] * al + ps;
      Oacc[rg] *= al;
    }
    // PV: P (A-layout via LDS round trip) x V^T, k=32 fully used
    #pragma unroll
    for (int half = 0; half < 2; ++half) {
      bf8 pa = *(const bf8*)&Ps[w][r16][half * 32 + quad * 8];
      bf8 vb = mk8(*(const ushort4*)&Vt[r16][half * 32 + quad * 8],
                   *(const ushort4*)&Vt[r16][half * 32 + quad * 8 + 4]);
      Oacc = __builtin_amdgcn_mfma_f32_16x16x32_bf16(pa, vb, Oacc, 0, 0, 0);
    }
  }

  // write unnormalized partials
  #pragma unroll
  for (int rg = 0; rg < 4; ++rg) {
    int gi = i0 + w * 16 + quad * 4 + rg;
    if (gi < N1) {
      size_t base = ((size_t)(bh * NSPLIT + s) * N1 + gi);
      Opart[base * 16 + r16] = Oacc[rg];
      if (r16 == 0) {
        mpart[base] = mrun[rg];
        lpart[base] = lrun[rg];
      }
    }
  }
}

// ---------------------------------------------------------------- combine split partials (exact fp32)
__global__ void attn_combine_kernel(const float* __restrict__ Opart,
                                    const float* __restrict__ mpart,
                                    const float* __restrict__ lpart,
                                    float* __restrict__ ctx) {
  int idx = blockIdx.x * 256 + threadIdx.x;
  if (idx >= BB * NH * N1) return;
  int q = idx % N1; int bh = idx / N1; int h = bh & 7; int b = bh >> 3;
  float ms[NSPLIT];
  float m = -BIGF;
  #pragma unroll
  for (int s = 0; s < NSPLIT; ++s) {
    ms[s] = mpart[(size_t)(bh * NSPLIT + s) * N1 + q];
    m = fmaxf(m, ms[s]);
  }
  float l = 0.f;
  float o[16];
  #pragma unroll
  for (int d = 0; d < DK; ++d) o[d] = 0.f;
  #pragma unroll
  for (int s = 0; s < NSPLIT; ++s) {
    float wgt = __expf(ms[s] - m);
    size_t base = (size_t)(bh * NSPLIT + s) * N1 + q;
    l += lpart[base] * wgt;
    const float* op = Opart + base * 16;
    #pragma unroll
    for (int d = 0; d < DK; ++d) o[d] += op[d] * wgt;
  }
  float inv = 1.0f / l;
  float* orow = ctx + ((size_t)b * N1 + q) * DM + h * DK;
  #pragma unroll
  for (int d = 0; d < DK; ++d) orow[d] = o[d] * inv;
}

// ---------------------------------------------------------------- instance norm (+pool, +g-update)
__global__ void inorm_kernel(float* __restrict__ X, const float* __restrict__ w,
                             const float* __restrict__ b_, float* __restrict__ pool,
                             int do_g) {
  int d = blockIdx.x; int bb = blockIdx.y; int lane = threadIdx.x;  // 64 threads
  float g_old = X[((size_t)bb * N1 + NN) * DM + d];
  float s = 0.f;
  for (int n = lane; n < N1; n += 64) s += X[((size_t)bb * N1 + n) * DM + d];
  #pragma unroll
  for (int o = 1; o < 64; o <<= 1) s += __shfl_xor(s, o);
  float mu = s * (1.0f / N1);
  float v = 0.f;
  for (int n = lane; n < N1; n += 64) {
    float tt = X[((size_t)bb * N1 + n) * DM + d] - mu;
    v += tt * tt;
  }
  #pragma unroll
  for (int o = 1; o < 64; o <<= 1) v += __shfl_xor(v, o);
  float var = v * (1.0f / N1);
  float scv = rsqrtf(var + 1e-5f) * w[d];
  float sh = b_[d];
  for (int n = lane; n < N1; n += 64) {
    size_t id = ((size_t)bb * N1 + n) * DM + d;
    X[id] = (X[id] - mu) * scv + sh;
  }
  if (lane == 0) {
    float hmean = ((s - g_old) * (1.0f / NN) - mu) * scv + sh;
    if (pool) pool[bb * DM + d] = hmean;
    if (do_g) X[((size_t)bb * N1 + NN) * DM + d] += hmean;
  }
}

// ---------------------------------------------------------------- p_multi
__global__ void pmulti_kernel(const float* __restrict__ pools, float* __restrict__ pm,
                              float* __restrict__ out_pm) {
  int idx = blockIdx.x * 64 + threadIdx.x;
  if (idx >= BB * DM) return;
  float v = (pools[idx] + pools[BB * DM + idx] + pools[2 * BB * DM + idx]) * (1.0f / 3.0f);
  pm[idx] = v;
  out_pm[idx] = v;
}

// ---------------------------------------------------------------- tmp2 = h + p_multi
__global__ void addpm_kernel(const float* __restrict__ X, const float* __restrict__ pm,
                             float* __restrict__ tmp2) {
  int idx = blockIdx.x * 256 + threadIdx.x;
  if (idx >= BB * NN * DM) return;
  int d = idx % DM; int n = (idx / DM) % NN; int b = idx / (DM * NN);
  tmp2[idx] = X[((size_t)b * N1 + n) * DM + d] + pm[b * DM + d];
}

// ================================================================ launch
extern "C" void kernel_launch(void* const* d_in, const int* in_sizes, int n_in,
                              void* d_out, int out_size, void* d_ws, size_t ws_size,
                              hipStream_t stream) {
  const float* coords = (const float*)d_in[0];
  const float* inW    = (const float*)d_in[1];
  const float* inb    = (const float*)d_in[2];
  const float* gnode  = (const float*)d_in[3];
  const float* Wq     = (const float*)d_in[4];
  const float* Wk     = (const float*)d_in[5];
  const float* Wv     = (const float*)d_in[6];
  const float* Wo     = (const float*)d_in[7];
  const float* emb    = (const float*)d_in[8];
  const float* W1     = (const float*)d_in[9];
  const float* b1     = (const float*)d_in[10];
  const float* W2     = (const float*)d_in[11];
  const float* b2     = (const float*)d_in[12];
  const float* n1w    = (const float*)d_in[13];
  const float* n1b    = (const float*)d_in[14];
  const float* n2w    = (const float*)d_in[15];
  const float* n2b    = (const float*)d_in[16];
  const float* outW   = (const float*)d_in[17];
  const float* outb   = (const float*)d_in[18];
  float* out = (float*)d_out;

  char* wsp = (char*)d_ws;
  size_t off = 0;
  auto alloc = [&](size_t bytes) -> void* {
    off = (off + 255) & ~(size_t)255;
    void* p = wsp + off;
    off += bytes;
    return p;
  };
  const size_t XB = (size_t)BB * N1 * DM * 4;
  float* X0   = (float*)alloc(XB);
  float* X1   = (float*)alloc(XB);
  float* Qb   = (float*)alloc(XB);
  float* Kbuf = (float*)alloc(XB);
  float* Vbuf = (float*)alloc(XB);
  float* Cb   = (float*)alloc(XB);
  float* Yb   = (float*)alloc(XB);
  float* Fb   = (float*)alloc((size_t)BB * N1 * DFF * 4);   // also attn Opart (disjoint in time)
  unsigned char* buckp = (unsigned char*)alloc((size_t)BB * N1 * BSTR);
  unsigned long long* adj = (unsigned long long*)alloc((size_t)BB * N1 * ADJW * 8);
  u32* connb = (u32*)alloc((size_t)BB * N1 * MW * 4);
  float* sqb   = (float*)alloc((size_t)BB * NN * 4);
  float* pools = (float*)alloc((size_t)NLAYERS * BB * DM * 4);
  float* pm    = (float*)alloc((size_t)BB * DM * 4);
  float* tmp   = (float*)alloc((size_t)BB * NN * DM * 4);   // also attn m/l partials

  float* Opart = Fb;                       // BB*NH*NSPLIT*N1*16 = 1,049,600 floats = Fb size
  float* mpart = tmp;                      // BB*NH*NSPLIT*N1 = 65,600 floats
  float* lpart = tmp + 65600;

  embed_kernel<<<(BB * N1 * DM + 255) / 256, 256, 0, stream>>>(coords, inW, inb, gnode, X0);
  bucket_kernel<<<(BB * N1 * BSTR + 255) / 256, 256, 0, stream>>>(coords, buckp);
  g_update_kernel<<<dim3(DM, BB), 64, 0, stream>>>(X0);   // layer 0 g-update

  float* Xin = X0; float* Xout = X1;
  const int M = BB * N1;
  const int GM = (M + BMT - 1) / BMT;   // 65
  for (int l = 0; l < NLAYERS; ++l) {
    hipMemsetAsync(adj, 0, (size_t)BB * N1 * ADJW * 8, stream);
    rowsq_kernel<<<(BB * NN + 63) / 64, 64, 0, stream>>>(Xin, sqb);
    knn_kernel<<<BB * NN / 4, 256, 0, stream>>>(Xin, sqb, adj);
    connb_kernel<<<(BB * N1 + 255) / 256, 256, 0, stream>>>(adj, connb);

    gemm_qkv_kernel<<<dim3(GM, DM / BNT, 3), 256, 0, stream>>>(
        Xin, Wq + (size_t)l * DM * DM, Wk + (size_t)l * DM * DM, Wv + (size_t)l * DM * DM,
        Qb, Kbuf, Vbuf, M);

    attn_kernel<<<dim3(33, NH * BB, NSPLIT), 128, 0, stream>>>(
        Qb, Kbuf, Vbuf, emb + (size_t)l * NBUK * DM, buckp, connb, Opart, mpart, lpart);
    attn_combine_kernel<<<(BB * NH * N1 + 255) / 256, 256, 0, stream>>>(
        Opart, mpart, lpart, Cb);

    gemm_kernel<<<dim3(GM, DM / BNT), 256, 0, stream>>>(
        Cb, Wo + (size_t)l * DM * DM, nullptr, Xin, Yb, M, DM, DM, 0);
    inorm_kernel<<<dim3(DM, BB), 64, 0, stream>>>(Yb, n1w + l * DM, n1b + l * DM, nullptr, 0);

    gemm_kernel<<<dim3(GM, DFF / BNT), 256, 0, stream>>>(
        Yb, W1 + (size_t)l * DFF * DM, b1 + l * DFF, nullptr, Fb, M, DM, DFF, 1);
    gemm_kernel<<<dim3(GM, DM / BNT), 256, 0, stream>>>(
        Fb, W2 + (size_t)l * DM * DFF, b2 + l * DM, Yb, Xout, M, DFF, DM, 0);
    // fused: inorm + pool + g-update for next layer
    inorm_kernel<<<dim3(DM, BB), 64, 0, stream>>>(Xout, n2w + l * DM, n2b + l * DM,
                                                  pools + (size_t)l * BB * DM, 1);

    float* t2 = Xin; Xin = Xout; Xout = t2;
  }

  pmulti_kernel<<<(BB * DM + 63) / 64, 64, 0, stream>>>(pools, pm, out + (size_t)BB * NN * DM);
  addpm_kernel<<<(BB * NN * DM + 255) / 256, 256, 0, stream>>>(Xin, pm, tmp);
  gemm_kernel<<<dim3((BB * NN + BMT - 1) / BMT, DM / BNT), 256, 0, stream>>>(
      tmp, outW, outb, nullptr, out, BB * NN, DM, DM, 0);
}